// Round 10
// baseline (578.514 us; speedup 1.0000x reference)
//
#include <hip/hip_runtime.h>
#include <hip/hip_bf16.h>
#include <math.h>

typedef float f32x4 __attribute__((ext_vector_type(4)));
typedef short s16x8 __attribute__((ext_vector_type(8)));
typedef short s16x4 __attribute__((ext_vector_type(4)));

#define TSEQ 2048

__device__ __forceinline__ unsigned short f2bf(float f){
  unsigned int u = __builtin_bit_cast(unsigned int, f);
  u += 0x7FFFu + ((u >> 16) & 1u);
  return (unsigned short)(u >> 16);
}
__device__ __forceinline__ float sigf(float x){ return 1.0f / (1.0f + __expf(-x)); }
__device__ __forceinline__ float wredsum(float x){
  #pragma unroll
  for (int off = 32; off > 0; off >>= 1) x += __shfl_xor(x, off);
  return x;
}

// 16-lane-group sum via DPP — no LDS.
template<int CTRL>
__device__ __forceinline__ float dpp_add(float x){
  int v = __builtin_amdgcn_update_dpp(0, __builtin_bit_cast(int, x), CTRL, 0xF, 0xF, true);
  return x + __builtin_bit_cast(float, v);
}
__device__ __forceinline__ float red16(float x){
  x = dpp_add<0xB1>(x);   // quad_perm [1,0,3,2]
  x = dpp_add<0x4E>(x);   // quad_perm [2,3,0,1]
  x = dpp_add<0x124>(x);  // row_ror:4
  x = dpp_add<0x128>(x);  // row_ror:8
  return x;
}

// async global->LDS, 4B per lane: LDS dest = wave-uniform base + lane*4.
__device__ __forceinline__ void g2l(const float* gp, float* lp){
  __builtin_amdgcn_global_load_lds(
    (const __attribute__((address_space(1))) unsigned int*)gp,
    (__attribute__((address_space(3))) unsigned int*)lp, 4, 0, 0);
}
// async global->LDS, 16B per lane: LDS dest = wave-uniform base + lane*16.
__device__ __forceinline__ void g2l16(const unsigned short* gp, void* lp){
  __builtin_amdgcn_global_load_lds(
    (const __attribute__((address_space(1))) unsigned int*)gp,
    (__attribute__((address_space(3))) unsigned int*)lp, 16, 0, 0);
}

// ---------------- w0 prefix-scan (C=1024) ----------------
__global__ void w0_scan_k(const float* __restrict__ w0b, const float* __restrict__ w0d,
                          float* __restrict__ w0){
  __shared__ float buf[1024];
  int i = threadIdx.x;
  float v = 0.f;
  if (i > 0){
    float d = w0d[i-1];
    v = (d > 20.f) ? d : log1pf(__expf(d));   // softplus
  }
  buf[i] = v;
  __syncthreads();
  for (int off = 1; off < 1024; off <<= 1){
    float t = (i >= off) ? buf[i - off] : 0.f;
    __syncthreads();
    buf[i] += t;
    __syncthreads();
  }
  w0[i] = w0b[0] + buf[i];
}

// ---------------- convert all weights f32 -> bf16 (once) ----------------
struct WCvtArgs { const float* src[10]; };
__constant__ const int WCSUM[11] = {0, 1048576, 2097152, 3145728, 4194304,
                                    4259840, 4325376, 4390912, 4456448, 4620288, 4784128};
#define WTOT 4784128

__global__ __launch_bounds__(256) void wcvt_k(WCvtArgs args, unsigned short* __restrict__ dst){
  const int e0 = (blockIdx.x * 256 + threadIdx.x) * 4;
  #pragma unroll
  for (int i = 0; i < 10; i++){
    if (e0 < WCSUM[i+1]){
      const f32x4 q = *(const f32x4*)(args.src[i] + (e0 - WCSUM[i]));
      s16x4 o; o[0]=(short)f2bf(q.x); o[1]=(short)f2bf(q.y); o[2]=(short)f2bf(q.z); o[3]=(short)f2bf(q.w);
      *(s16x4*)(dst + e0) = o;
      return;
    }
  }
}

// ---------------- token-shift mix -> 6 bf16 arrays (once) ----------------
__global__ __launch_bounds__(256) void prep_k(
    const float* __restrict__ x,
    const float* __restrict__ cr, const float* __restrict__ cw, const float* __restrict__ ck,
    const float* __restrict__ cv, const float* __restrict__ ca, const float* __restrict__ cg,
    unsigned short* __restrict__ xr, unsigned short* __restrict__ xw, unsigned short* __restrict__ xk,
    unsigned short* __restrict__ xv, unsigned short* __restrict__ xa, unsigned short* __restrict__ xg)
{
  const int m = blockIdx.x;
  const int c = threadIdx.x * 4;
  const size_t ix = (size_t)m * 1024 + c;
  const f32x4 q = *(const f32x4*)(x + ix);
  f32x4 s = {0.f,0.f,0.f,0.f};
  if ((m & (TSEQ - 1)) != 0) s = *(const f32x4*)(x + ix - 1024);
  const f32x4 d = s - q;
  #define DO_MIX(coef, out) { \
    const f32x4 mc = *(const f32x4*)(coef + c); \
    s16x4 o; \
    o[0]=(short)f2bf(fmaf(d.x, mc.x, q.x)); o[1]=(short)f2bf(fmaf(d.y, mc.y, q.y)); \
    o[2]=(short)f2bf(fmaf(d.z, mc.z, q.z)); o[3]=(short)f2bf(fmaf(d.w, mc.w, q.w)); \
    *(s16x4*)(out + ix) = o; }
  DO_MIX(cr, xr); DO_MIX(cw, xw); DO_MIX(ck, xk);
  DO_MIX(cv, xv); DO_MIX(ca, xa); DO_MIX(cg, xg);
  #undef DO_MIX
}

// ---------------- bf16 MFMA GEMM, global_load_lds + double buffer ----------------
#define EPI_F32 0
#define EPI_BF16 1
#define EPI_TANH_BF16 2
#define EPI_SIG_BF16 3
#define EPI_SIGBIAS_F32 4
#define EPI_DECAY_F32 5

template<int EPI>
__global__ __launch_bounds__(256) void gemm_k(
    const unsigned short* __restrict__ ABF,    // (M,K) bf16
    const unsigned short* __restrict__ BBF,    // (N,K) bf16 (rows beyond N readable)
    void* __restrict__ Cout,
    const float* __restrict__ bias, const float* __restrict__ w0,
    int M, int N, int K)
{
  __shared__ unsigned short As[2][128][32];    // linear (no pad): g2l dest layout
  __shared__ unsigned short Bs[2][128][32];
  const int tid  = threadIdx.x;
  const int m0   = blockIdx.y * 128;
  const int n0   = blockIdx.x * 128;
  const int srow = tid >> 2;                   // staging row 0..63
  const int scol = (tid & 3) << 3;             // staging col 0,8,16,24
  const int wofs = (tid >> 6) << 10;           // wave*1024 bytes within half-tile
  const int lane = tid & 63;
  const int wv   = tid >> 6;
  const int wr   = (wv >> 1) << 6;
  const int wc   = (wv & 1) << 6;
  const int lr   = lane & 15;
  const int lg   = lane >> 4;

  // stage one 128x32 bf16 tile (8KB) per matrix: 2 g2l16 per thread per matrix
#define STAGE(BUF, KOFF) { \
    const unsigned short* a0 = ABF + (size_t)(m0 + srow) * K + (KOFF) + scol; \
    const unsigned short* b0 = BBF + (size_t)(n0 + srow) * K + (KOFF) + scol; \
    g2l16(a0,                 (char*)&As[BUF][0][0] + wofs); \
    g2l16(a0 + (size_t)64*K,  (char*)&As[BUF][0][0] + 4096 + wofs); \
    g2l16(b0,                 (char*)&Bs[BUF][0][0] + wofs); \
    g2l16(b0 + (size_t)64*K,  (char*)&Bs[BUF][0][0] + 4096 + wofs); }

  f32x4 acc[4][4];
  #pragma unroll
  for (int i = 0; i < 4; i++)
    #pragma unroll
    for (int j = 0; j < 4; j++) acc[i][j] = f32x4{0.f, 0.f, 0.f, 0.f};

  STAGE(0, 0)
  __syncthreads();                             // drains vmcnt+lgkmcnt (compiler)

  int buf = 0;
  for (int k0 = 0; k0 < K; k0 += 32){
    if (k0 + 32 < K){ STAGE(buf ^ 1, k0 + 32) }
    s16x8 af[4], bfr[4];
    #pragma unroll
    for (int i = 0; i < 4; i++) af[i]  = *(const s16x8*)&As[buf][wr + i*16 + lr][lg*8];
    #pragma unroll
    for (int j = 0; j < 4; j++) bfr[j] = *(const s16x8*)&Bs[buf][wc + j*16 + lr][lg*8];
    #pragma unroll
    for (int i = 0; i < 4; i++)
      #pragma unroll
      for (int j = 0; j < 4; j++)
        acc[i][j] = __builtin_amdgcn_mfma_f32_16x16x32_bf16(af[i], bfr[j], acc[i][j], 0, 0, 0);
    __syncthreads();                           // next buf staged & this buf free
    buf ^= 1;
  }
#undef STAGE

  #pragma unroll
  for (int i = 0; i < 4; i++){
    const int mb = m0 + wr + i*16 + lg*4;
    #pragma unroll
    for (int j = 0; j < 4; j++){
      const int n = n0 + wc + j*16 + lr;
      if (n < N){
        #pragma unroll
        for (int q = 0; q < 4; q++){
          const int m = mb + q;
          const float val = acc[i][j][q];
          const size_t oix = (size_t)m * N + n;
          if constexpr (EPI == EPI_F32)            ((float*)Cout)[oix] = val;
          else if constexpr (EPI == EPI_BF16)      ((unsigned short*)Cout)[oix] = f2bf(val);
          else if constexpr (EPI == EPI_TANH_BF16) ((unsigned short*)Cout)[oix] = f2bf(tanhf(val));
          else if constexpr (EPI == EPI_SIG_BF16)  ((unsigned short*)Cout)[oix] = f2bf(sigf(val));
          else if constexpr (EPI == EPI_SIGBIAS_F32) ((float*)Cout)[oix] = sigf(val + bias[n]);
          else if constexpr (EPI == EPI_DECAY_F32){
            float z = val + bias[n] + w0[n];
            ((float*)Cout)[oix] = expf(-0.60653065971263342f * sigf(z));
          }
        }
      }
    }
  }
}

// ---------------- kk normalize (NEGATED), k scale, b = kk*a ----------------
__global__ __launch_bounds__(256) void kkprep_k(
    float* __restrict__ k, float* __restrict__ ab, float* __restrict__ kk,
    const float* __restrict__ kkc, const float* __restrict__ kac)
{
  const int row  = blockIdx.x * 4 + (threadIdx.x >> 6);
  const int lane = threadIdx.x & 63;
  const size_t idx = (size_t)row * 64 + lane;
  const int c = ((row & 15) << 6) + lane;
  const float kv = k[idx];
  const float av = ab[idx];
  const float t  = kv * kkc[c];
  const float ss = wredsum(t * t);
  const float kkv = t / fmaxf(sqrtf(ss), 1e-12f);
  kk[idx] = -kkv;         // a_in = -kk, pre-negated for the scan
  k[idx]  = kv * (1.f + (av - 1.f) * kac[c]);
  ab[idx] = kkv * av;     // b_in
}

// ---------------- RWKV-7 scan: LDS ring + g2l, 4-step regions, batched stores ----
// 8-slot ring in two halves. Per region: one vmcnt(24) (stores no longer pollute:
// only 1 store per 16 steps) -> PREF 4 slots -> 4 STEPs -> refill 4 slots.
// NO sched_barriers: compiler interleaves PREF/STEP/refill within the region.
// o outputs collected via lane-select; one 64-lane store per 16 steps.
__global__ __launch_bounds__(64) void scan_k(
    const float* __restrict__ r, const float* __restrict__ w, const float* __restrict__ k,
    const float* __restrict__ v, const float* __restrict__ b, const float* __restrict__ kk,
    float* __restrict__ o)
{
  const int lane = threadIdx.x;
  const int L    = lane & 15;
  const int g    = lane >> 4;
  const int bh   = blockIdx.x & 31;            // b*16+h
  const int grp  = blockIdx.x >> 5;            // 0..15 row group
  const int bb   = bh >> 4, hh = bh & 15;
  const size_t base = (size_t)bb * TSEQ * 1024 + hh * 64;
  const int vq   = 4 * L;
  const int vrow = grp * 4 + g;

  __shared__ float lds[8][6][64];              // 12 KB ring

  int tload = 0;                               // next step index to load

#define G2L6(SLOT) { \
    const int tc = (tload < TSEQ) ? tload : (TSEQ - 1); \
    const size_t off = base + (size_t)tc * 1024 + lane; \
    g2l(r  + off, &lds[SLOT][0][0]); \
    g2l(w  + off, &lds[SLOT][1][0]); \
    g2l(k  + off, &lds[SLOT][2][0]); \
    g2l(b  + off, &lds[SLOT][3][0]); \
    g2l(kk + off, &lds[SLOT][4][0]); \
    g2l(v  + off, &lds[SLOT][5][0]); \
    tload++; }

  f32x4 Rg[8], Wg[8], Kg[8], Bg[8], Ag[8];
  float Vg[8];

#define PREF(SLOT, SET) { \
    Rg[SET] = *(const f32x4*)&lds[SLOT][0][vq]; \
    Wg[SET] = *(const f32x4*)&lds[SLOT][1][vq]; \
    Kg[SET] = *(const f32x4*)&lds[SLOT][2][vq]; \
    Bg[SET] = *(const f32x4*)&lds[SLOT][3][vq]; \
    Ag[SET] = *(const f32x4*)&lds[SLOT][4][vq]; \
    Vg[SET] = lds[SLOT][5][vrow]; }

  f32x4 S = {0.f, 0.f, 0.f, 0.f};
  float oreg = 0.f;

#define STEP(I, SIDX) { \
    const float p = fmaf(S.y, Ag[I].y, S.x * Ag[I].x) + fmaf(S.w, Ag[I].w, S.z * Ag[I].z); \
    const float sa = red16(p); \
    const float cv = Vg[I]; \
    S.x = fmaf(S.x, Wg[I].x, fmaf(sa, Bg[I].x, cv * Kg[I].x)); \
    S.y = fmaf(S.y, Wg[I].y, fmaf(sa, Bg[I].y, cv * Kg[I].y)); \
    S.z = fmaf(S.z, Wg[I].z, fmaf(sa, Bg[I].z, cv * Kg[I].z)); \
    S.w = fmaf(S.w, Wg[I].w, fmaf(sa, Bg[I].w, cv * Kg[I].w)); \
    const float q = fmaf(S.y, Rg[I].y, S.x * Rg[I].x) + fmaf(S.w, Rg[I].w, S.z * Rg[I].z); \
    const float oo = red16(q); \
    oreg = (L == (SIDX)) ? oo : oreg; }

#define VMW(N) asm volatile("s_waitcnt vmcnt(" #N ")" ::: "memory");

  // prologue: slots 0..7 <- steps 0..7; prime sets 0-3; refill slots 0-3 <- 8..11
  G2L6(0) G2L6(1) G2L6(2) G2L6(3) G2L6(4) G2L6(5) G2L6(6) G2L6(7)
  VMW(24)
  PREF(0,0) PREF(1,1) PREF(2,2) PREF(3,3)
  G2L6(0) G2L6(1) G2L6(2) G2L6(3)

  for (int tile = 0; tile < TSEQ/16; ++tile){
    VMW(24)
    PREF(4,4) PREF(5,5) PREF(6,6) PREF(7,7)
    STEP(0,0) STEP(1,1) STEP(2,2) STEP(3,3)
    G2L6(4) G2L6(5) G2L6(6) G2L6(7)
    VMW(24)
    PREF(0,0) PREF(1,1) PREF(2,2) PREF(3,3)
    STEP(4,4) STEP(5,5) STEP(6,6) STEP(7,7)
    G2L6(0) G2L6(1) G2L6(2) G2L6(3)
    VMW(24)
    PREF(4,4) PREF(5,5) PREF(6,6) PREF(7,7)
    STEP(0,8) STEP(1,9) STEP(2,10) STEP(3,11)
    G2L6(4) G2L6(5) G2L6(6) G2L6(7)
    VMW(24)
    PREF(0,0) PREF(1,1) PREF(2,2) PREF(3,3)
    STEP(4,12) STEP(5,13) STEP(6,14) STEP(7,15)
    G2L6(0) G2L6(1) G2L6(2) G2L6(3)
    o[base + (size_t)(tile*16 + L) * 1024 + vrow] = oreg;   // 1 store / 16 steps
  }

#undef G2L6
#undef PREF
#undef STEP
#undef VMW
}

// ---------------- GroupNorm + bonus + gate -> y (bf16) ----------------
__global__ __launch_bounds__(256) void gnout_k(
    const float* __restrict__ o, const float* __restrict__ r, const float* __restrict__ k,
    const float* __restrict__ v, const float* __restrict__ g,
    const float* __restrict__ rk, const float* __restrict__ gnw, const float* __restrict__ gnb,
    unsigned short* __restrict__ y)
{
  const int row  = blockIdx.x * 4 + (threadIdx.x >> 6);
  const int lane = threadIdx.x & 63;
  const size_t idx = (size_t)row * 64 + lane;
  const int c = ((row & 15) << 6) + lane;
  const float ov  = o[idx];
  const float mu  = wredsum(ov) * 0.015625f;
  const float d   = ov - mu;
  const float var = wredsum(d * d) * 0.015625f;
  const float on  = d * rsqrtf(var + 6.4e-4f) * gnw[c] + gnb[c];   // eps = D*1e-5
  const float s   = wredsum(r[idx] * k[idx] * rk[c]);
  const float yv  = (on + s * v[idx]) * g[idx];
  y[idx] = f2bf(yv);
}

extern "C" void kernel_launch(void* const* d_in, const int* in_sizes, int n_in,
                              void* d_out, int out_size, void* d_ws, size_t ws_size,
                              hipStream_t stream)
{
  const float* x    = (const float*)d_in[0];
  const float* x_r  = (const float*)d_in[1];
  const float* x_w  = (const float*)d_in[2];
  const float* x_k  = (const float*)d_in[3];
  const float* x_v  = (const float*)d_in[4];
  const float* x_a  = (const float*)d_in[5];
  const float* x_g  = (const float*)d_in[6];
  const float* k_k  = (const float*)d_in[7];
  const float* k_a  = (const float*)d_in[8];
  const float* r_k  = (const float*)d_in[9];
  const float* Wr   = (const float*)d_in[10];
  const float* Wk   = (const float*)d_in[11];
  const float* Wv   = (const float*)d_in[12];
  const float* Wo   = (const float*)d_in[13];
  const float* wA   = (const float*)d_in[14];
  const float* wB   = (const float*)d_in[15];
  const float* wbias= (const float*)d_in[16];
  const float* aA   = (const float*)d_in[17];
  const float* aB   = (const float*)d_in[18];
  const float* abias= (const float*)d_in[19];
  const float* gA   = (const float*)d_in[20];
  const float* gB   = (const float*)d_in[21];
  const float* gnw  = (const float*)d_in[22];
  const float* gnb  = (const float*)d_in[23];
  const float* w0b  = (const float*)d_in[24];
  const float* w0d  = (const float*)d_in[25];

  char* ws = (char*)d_ws;
  const size_t MB = 1024ull * 1024ull;
  const size_t KB = 1024ull;
  float* r_  = (float*)(ws +   0*MB);
  float* k_  = (float*)(ws +  16*MB);
  float* v_  = (float*)(ws +  32*MB);
  float* wd_ = (float*)(ws +  48*MB);   // decay (overlaps dead xk_)
  float* ab_ = (float*)(ws +  64*MB);   // a, then b (in place)
  float* kk_ = (float*)(ws +  80*MB);   // (overlaps dead xa_/xg_)
  float* o_  = (float*)(ws +  96*MB);   // (overlaps dead xv_/xw_)
  float* g_  = (float*)(ws + 112*MB);
  unsigned short* y_   = (unsigned short*)(ws + 128*MB);   // (overlaps dead xr_)
  unsigned short* wl1_ = (unsigned short*)(ws + 136*MB);
  unsigned short* al1_ = (unsigned short*)(ws + 136*MB + 512*KB);
  unsigned short* gl1_ = (unsigned short*)(ws + 137*MB);
  float*          w0_  = (float*)(ws + 138*MB + 512*KB);
  unsigned short* wbf_ = (unsigned short*)(ws + 139*MB);   // all weights bf16 (~9.6MB)
  // mixed bf16 inputs (8MB each), carved from regions written later:
  unsigned short* xr_ = (unsigned short*)(ws + 128*MB);    // dead before y_ write
  unsigned short* xw_ = (unsigned short*)(ws + 104*MB);    // dead before o_ write
  unsigned short* xk_ = (unsigned short*)(ws +  48*MB);    // dead before wd_ write
  unsigned short* xv_ = (unsigned short*)(ws +  96*MB);    // dead before o_ write
  unsigned short* xa_ = (unsigned short*)(ws +  80*MB);    // dead before kk_ write
  unsigned short* xg_ = (unsigned short*)(ws +  88*MB);    // dead before kk_ write

  // bf16 weight offsets (elements)
  const unsigned short* bWr = wbf_ + 0;
  const unsigned short* bWk = wbf_ + 1048576;
  const unsigned short* bWv = wbf_ + 2097152;
  const unsigned short* bWo = wbf_ + 3145728;
  const unsigned short* bwA = wbf_ + 4194304;
  const unsigned short* bwB = wbf_ + 4259840;
  const unsigned short* baA = wbf_ + 4325376;
  const unsigned short* baB = wbf_ + 4390912;
  const unsigned short* bgA = wbf_ + 4456448;
  const unsigned short* bgB = wbf_ + 4620288;

  const dim3 blk(256);
  const dim3 gBig(8, 32), gN64(1, 32), gN160(2, 32);

  w0_scan_k<<<dim3(1), dim3(1024), 0, stream>>>(w0b, w0d, w0_);

  WCvtArgs wargs;
  wargs.src[0]=Wr; wargs.src[1]=Wk; wargs.src[2]=Wv; wargs.src[3]=Wo;
  wargs.src[4]=wA; wargs.src[5]=wB; wargs.src[6]=aA; wargs.src[7]=aB;
  wargs.src[8]=gA; wargs.src[9]=gB;
  wcvt_k<<<dim3(WTOT/4/256), blk, 0, stream>>>(wargs, wbf_);

  prep_k<<<dim3(4096), blk, 0, stream>>>(x, x_r, x_w, x_k, x_v, x_a, x_g,
                                         xr_, xw_, xk_, xv_, xa_, xg_);

  // r, k, v projections
  gemm_k<EPI_F32><<<gBig, blk, 0, stream>>>(xr_, bWr, r_, nullptr, nullptr, 4096, 1024, 1024);
  gemm_k<EPI_F32><<<gBig, blk, 0, stream>>>(xk_, bWk, k_, nullptr, nullptr, 4096, 1024, 1024);
  gemm_k<EPI_F32><<<gBig, blk, 0, stream>>>(xv_, bWv, v_, nullptr, nullptr, 4096, 1024, 1024);

  // decay LoRA: tanh(xw@A^T) -> @B^T + bias + w0 -> decay
  gemm_k<EPI_TANH_BF16><<<gN64, blk, 0, stream>>>(xw_, bwA, wl1_, nullptr, nullptr, 4096, 64, 1024);
  gemm_k<EPI_DECAY_F32><<<gBig, blk, 0, stream>>>(wl1_, bwB, wd_, wbias, w0_, 4096, 1024, 64);

  // a LoRA: (xa@A^T) -> sigmoid(@B^T + bias)
  gemm_k<EPI_BF16><<<gN64, blk, 0, stream>>>(xa_, baA, al1_, nullptr, nullptr, 4096, 64, 1024);
  gemm_k<EPI_SIGBIAS_F32><<<gBig, blk, 0, stream>>>(al1_, baB, ab_, abias, nullptr, 4096, 1024, 64);

  // g LoRA: sigmoid(xg@A^T) -> @B^T
  gemm_k<EPI_SIG_BF16><<<gN160, blk, 0, stream>>>(xg_, bgA, gl1_, nullptr, nullptr, 4096, 160, 1024);
  gemm_k<EPI_F32><<<gBig, blk, 0, stream>>>(gl1_, bgB, g_, nullptr, nullptr, 4096, 1024, 160);

  // kk normalize (negated) + k scale + b
  kkprep_k<<<dim3(16384), blk, 0, stream>>>(k_, ab_, kk_, k_k, k_a);

  // sequential recurrence (LDS-ring, 4-step regions, batched stores)
  scan_k<<<dim3(512), dim3(64), 0, stream>>>(r_, wd_, k_, v_, ab_, kk_, o_);

  // GroupNorm + bonus + gate
  gnout_k<<<dim3(16384), blk, 0, stream>>>(o_, r_, k_, v_, g_, r_k, gnw, gnb, y_);

  // output projection
  gemm_k<EPI_F32><<<gBig, blk, 0, stream>>>(y_, bWo, (float*)d_out, nullptr, nullptr, 4096, 1024, 1024);
}

// Round 11
// 578.403 us; speedup vs baseline: 1.0002x; 1.0002x over previous
//
#include <hip/hip_runtime.h>
#include <hip/hip_bf16.h>
#include <math.h>

typedef float f32x4 __attribute__((ext_vector_type(4)));
typedef short s16x8 __attribute__((ext_vector_type(8)));
typedef short s16x4 __attribute__((ext_vector_type(4)));

#define TSEQ 2048

__device__ __forceinline__ unsigned short f2bf(float f){
  unsigned int u = __builtin_bit_cast(unsigned int, f);
  u += 0x7FFFu + ((u >> 16) & 1u);
  return (unsigned short)(u >> 16);
}
__device__ __forceinline__ float sigf(float x){ return 1.0f / (1.0f + __expf(-x)); }
__device__ __forceinline__ float wredsum(float x){
  #pragma unroll
  for (int off = 32; off > 0; off >>= 1) x += __shfl_xor(x, off);
  return x;
}

// 16-lane-group sum via DPP — no LDS.
template<int CTRL>
__device__ __forceinline__ float dpp_add(float x){
  int v = __builtin_amdgcn_update_dpp(0, __builtin_bit_cast(int, x), CTRL, 0xF, 0xF, true);
  return x + __builtin_bit_cast(float, v);
}
__device__ __forceinline__ float red16(float x){
  x = dpp_add<0xB1>(x);   // quad_perm [1,0,3,2]
  x = dpp_add<0x4E>(x);   // quad_perm [2,3,0,1]
  x = dpp_add<0x124>(x);  // row_ror:4
  x = dpp_add<0x128>(x);  // row_ror:8
  return x;
}

// async global->LDS, 4B per lane: LDS dest = wave-uniform base + lane*4.
__device__ __forceinline__ void g2l(const float* gp, float* lp){
  __builtin_amdgcn_global_load_lds(
    (const __attribute__((address_space(1))) unsigned int*)gp,
    (__attribute__((address_space(3))) unsigned int*)lp, 4, 0, 0);
}
// async global->LDS, 16B per lane: LDS dest = wave-uniform base + lane*16.
__device__ __forceinline__ void g2l16(const unsigned short* gp, void* lp){
  __builtin_amdgcn_global_load_lds(
    (const __attribute__((address_space(1))) unsigned int*)gp,
    (__attribute__((address_space(3))) unsigned int*)lp, 16, 0, 0);
}

// ---------------- w0 prefix-scan (C=1024) ----------------
__global__ void w0_scan_k(const float* __restrict__ w0b, const float* __restrict__ w0d,
                          float* __restrict__ w0){
  __shared__ float buf[1024];
  int i = threadIdx.x;
  float v = 0.f;
  if (i > 0){
    float d = w0d[i-1];
    v = (d > 20.f) ? d : log1pf(__expf(d));   // softplus
  }
  buf[i] = v;
  __syncthreads();
  for (int off = 1; off < 1024; off <<= 1){
    float t = (i >= off) ? buf[i - off] : 0.f;
    __syncthreads();
    buf[i] += t;
    __syncthreads();
  }
  w0[i] = w0b[0] + buf[i];
}

// ---------------- convert all weights f32 -> bf16 (once) ----------------
struct WCvtArgs { const float* src[10]; };
__constant__ const int WCSUM[11] = {0, 1048576, 2097152, 3145728, 4194304,
                                    4259840, 4325376, 4390912, 4456448, 4620288, 4784128};
#define WTOT 4784128

__global__ __launch_bounds__(256) void wcvt_k(WCvtArgs args, unsigned short* __restrict__ dst){
  const int e0 = (blockIdx.x * 256 + threadIdx.x) * 4;
  #pragma unroll
  for (int i = 0; i < 10; i++){
    if (e0 < WCSUM[i+1]){
      const f32x4 q = *(const f32x4*)(args.src[i] + (e0 - WCSUM[i]));
      s16x4 o; o[0]=(short)f2bf(q.x); o[1]=(short)f2bf(q.y); o[2]=(short)f2bf(q.z); o[3]=(short)f2bf(q.w);
      *(s16x4*)(dst + e0) = o;
      return;
    }
  }
}

// ---------------- token-shift mix -> 6 bf16 arrays (once) ----------------
__global__ __launch_bounds__(256) void prep_k(
    const float* __restrict__ x,
    const float* __restrict__ cr, const float* __restrict__ cw, const float* __restrict__ ck,
    const float* __restrict__ cv, const float* __restrict__ ca, const float* __restrict__ cg,
    unsigned short* __restrict__ xr, unsigned short* __restrict__ xw, unsigned short* __restrict__ xk,
    unsigned short* __restrict__ xv, unsigned short* __restrict__ xa, unsigned short* __restrict__ xg)
{
  const int m = blockIdx.x;
  const int c = threadIdx.x * 4;
  const size_t ix = (size_t)m * 1024 + c;
  const f32x4 q = *(const f32x4*)(x + ix);
  f32x4 s = {0.f,0.f,0.f,0.f};
  if ((m & (TSEQ - 1)) != 0) s = *(const f32x4*)(x + ix - 1024);
  const f32x4 d = s - q;
  #define DO_MIX(coef, out) { \
    const f32x4 mc = *(const f32x4*)(coef + c); \
    s16x4 o; \
    o[0]=(short)f2bf(fmaf(d.x, mc.x, q.x)); o[1]=(short)f2bf(fmaf(d.y, mc.y, q.y)); \
    o[2]=(short)f2bf(fmaf(d.z, mc.z, q.z)); o[3]=(short)f2bf(fmaf(d.w, mc.w, q.w)); \
    *(s16x4*)(out + ix) = o; }
  DO_MIX(cr, xr); DO_MIX(cw, xw); DO_MIX(ck, xk);
  DO_MIX(cv, xv); DO_MIX(ca, xa); DO_MIX(cg, xg);
  #undef DO_MIX
}

// ---------------- bf16 MFMA GEMM, global_load_lds + double buffer ----------------
#define EPI_F32 0
#define EPI_BF16 1
#define EPI_TANH_BF16 2
#define EPI_SIG_BF16 3
#define EPI_SIGBIAS_F32 4
#define EPI_DECAY_F32 5

template<int EPI>
__global__ __launch_bounds__(256) void gemm_k(
    const unsigned short* __restrict__ ABF,    // (M,K) bf16
    const unsigned short* __restrict__ BBF,    // (N,K) bf16 (rows beyond N readable)
    void* __restrict__ Cout,
    const float* __restrict__ bias, const float* __restrict__ w0,
    int M, int N, int K)
{
  __shared__ unsigned short As[2][128][32];    // linear (no pad): g2l dest layout
  __shared__ unsigned short Bs[2][128][32];
  const int tid  = threadIdx.x;
  const int m0   = blockIdx.y * 128;
  const int n0   = blockIdx.x * 128;
  const int srow = tid >> 2;                   // staging row 0..63
  const int scol = (tid & 3) << 3;             // staging col 0,8,16,24
  const int wofs = (tid >> 6) << 10;           // wave*1024 bytes within half-tile
  const int lane = tid & 63;
  const int wv   = tid >> 6;
  const int wr   = (wv >> 1) << 6;
  const int wc   = (wv & 1) << 6;
  const int lr   = lane & 15;
  const int lg   = lane >> 4;

  // stage one 128x32 bf16 tile (8KB) per matrix: 2 g2l16 per thread per matrix
#define STAGE(BUF, KOFF) { \
    const unsigned short* a0 = ABF + (size_t)(m0 + srow) * K + (KOFF) + scol; \
    const unsigned short* b0 = BBF + (size_t)(n0 + srow) * K + (KOFF) + scol; \
    g2l16(a0,                 (char*)&As[BUF][0][0] + wofs); \
    g2l16(a0 + (size_t)64*K,  (char*)&As[BUF][0][0] + 4096 + wofs); \
    g2l16(b0,                 (char*)&Bs[BUF][0][0] + wofs); \
    g2l16(b0 + (size_t)64*K,  (char*)&Bs[BUF][0][0] + 4096 + wofs); }

  f32x4 acc[4][4];
  #pragma unroll
  for (int i = 0; i < 4; i++)
    #pragma unroll
    for (int j = 0; j < 4; j++) acc[i][j] = f32x4{0.f, 0.f, 0.f, 0.f};

  STAGE(0, 0)
  __syncthreads();                             // drains vmcnt+lgkmcnt (compiler)

  int buf = 0;
  for (int k0 = 0; k0 < K; k0 += 32){
    if (k0 + 32 < K){ STAGE(buf ^ 1, k0 + 32) }
    s16x8 af[4], bfr[4];
    #pragma unroll
    for (int i = 0; i < 4; i++) af[i]  = *(const s16x8*)&As[buf][wr + i*16 + lr][lg*8];
    #pragma unroll
    for (int j = 0; j < 4; j++) bfr[j] = *(const s16x8*)&Bs[buf][wc + j*16 + lr][lg*8];
    #pragma unroll
    for (int i = 0; i < 4; i++)
      #pragma unroll
      for (int j = 0; j < 4; j++)
        acc[i][j] = __builtin_amdgcn_mfma_f32_16x16x32_bf16(af[i], bfr[j], acc[i][j], 0, 0, 0);
    __syncthreads();                           // next buf staged & this buf free
    buf ^= 1;
  }
#undef STAGE

  #pragma unroll
  for (int i = 0; i < 4; i++){
    const int mb = m0 + wr + i*16 + lg*4;
    #pragma unroll
    for (int j = 0; j < 4; j++){
      const int n = n0 + wc + j*16 + lr;
      if (n < N){
        #pragma unroll
        for (int q = 0; q < 4; q++){
          const int m = mb + q;
          const float val = acc[i][j][q];
          const size_t oix = (size_t)m * N + n;
          if constexpr (EPI == EPI_F32)            ((float*)Cout)[oix] = val;
          else if constexpr (EPI == EPI_BF16)      ((unsigned short*)Cout)[oix] = f2bf(val);
          else if constexpr (EPI == EPI_TANH_BF16) ((unsigned short*)Cout)[oix] = f2bf(tanhf(val));
          else if constexpr (EPI == EPI_SIG_BF16)  ((unsigned short*)Cout)[oix] = f2bf(sigf(val));
          else if constexpr (EPI == EPI_SIGBIAS_F32) ((float*)Cout)[oix] = sigf(val + bias[n]);
          else if constexpr (EPI == EPI_DECAY_F32){
            float z = val + bias[n] + w0[n];
            ((float*)Cout)[oix] = expf(-0.60653065971263342f * sigf(z));
          }
        }
      }
    }
  }
}

// ---------------- kk normalize (NEGATED), k scale, b = kk*a ----------------
__global__ __launch_bounds__(256) void kkprep_k(
    float* __restrict__ k, float* __restrict__ ab, float* __restrict__ kk,
    const float* __restrict__ kkc, const float* __restrict__ kac)
{
  const int row  = blockIdx.x * 4 + (threadIdx.x >> 6);
  const int lane = threadIdx.x & 63;
  const size_t idx = (size_t)row * 64 + lane;
  const int c = ((row & 15) << 6) + lane;
  const float kv = k[idx];
  const float av = ab[idx];
  const float t  = kv * kkc[c];
  const float ss = wredsum(t * t);
  const float kkv = t / fmaxf(sqrtf(ss), 1e-12f);
  kk[idx] = -kkv;         // a_in = -kk, pre-negated for the scan
  k[idx]  = kv * (1.f + (av - 1.f) * kac[c]);
  ab[idx] = kkv * av;     // b_in
}

// ---------------- RWKV-7 scan: LDS ring + g2l, 4-step regions, batched stores ----
// 8-slot ring in two halves. Per region: one vmcnt(24) (stores no longer pollute:
// only 1 store per 16 steps) -> PREF 4 slots -> 4 STEPs -> refill 4 slots.
// NO sched_barriers: compiler interleaves PREF/STEP/refill within the region.
// o outputs collected via lane-select; one 64-lane store per 16 steps.
__global__ __launch_bounds__(64) void scan_k(
    const float* __restrict__ r, const float* __restrict__ w, const float* __restrict__ k,
    const float* __restrict__ v, const float* __restrict__ b, const float* __restrict__ kk,
    float* __restrict__ o)
{
  const int lane = threadIdx.x;
  const int L    = lane & 15;
  const int g    = lane >> 4;
  const int bh   = blockIdx.x & 31;            // b*16+h
  const int grp  = blockIdx.x >> 5;            // 0..15 row group
  const int bb   = bh >> 4, hh = bh & 15;
  const size_t base = (size_t)bb * TSEQ * 1024 + hh * 64;
  const int vq   = 4 * L;
  const int vrow = grp * 4 + g;

  __shared__ float lds[8][6][64];              // 12 KB ring

  int tload = 0;                               // next step index to load

#define G2L6(SLOT) { \
    const int tc = (tload < TSEQ) ? tload : (TSEQ - 1); \
    const size_t off = base + (size_t)tc * 1024 + lane; \
    g2l(r  + off, &lds[SLOT][0][0]); \
    g2l(w  + off, &lds[SLOT][1][0]); \
    g2l(k  + off, &lds[SLOT][2][0]); \
    g2l(b  + off, &lds[SLOT][3][0]); \
    g2l(kk + off, &lds[SLOT][4][0]); \
    g2l(v  + off, &lds[SLOT][5][0]); \
    tload++; }

  f32x4 Rg[8], Wg[8], Kg[8], Bg[8], Ag[8];
  float Vg[8];

#define PREF(SLOT, SET) { \
    Rg[SET] = *(const f32x4*)&lds[SLOT][0][vq]; \
    Wg[SET] = *(const f32x4*)&lds[SLOT][1][vq]; \
    Kg[SET] = *(const f32x4*)&lds[SLOT][2][vq]; \
    Bg[SET] = *(const f32x4*)&lds[SLOT][3][vq]; \
    Ag[SET] = *(const f32x4*)&lds[SLOT][4][vq]; \
    Vg[SET] = lds[SLOT][5][vrow]; }

  f32x4 S = {0.f, 0.f, 0.f, 0.f};
  float oreg = 0.f;

#define STEP(I, SIDX) { \
    const float p = fmaf(S.y, Ag[I].y, S.x * Ag[I].x) + fmaf(S.w, Ag[I].w, S.z * Ag[I].z); \
    const float sa = red16(p); \
    const float cv = Vg[I]; \
    S.x = fmaf(S.x, Wg[I].x, fmaf(sa, Bg[I].x, cv * Kg[I].x)); \
    S.y = fmaf(S.y, Wg[I].y, fmaf(sa, Bg[I].y, cv * Kg[I].y)); \
    S.z = fmaf(S.z, Wg[I].z, fmaf(sa, Bg[I].z, cv * Kg[I].z)); \
    S.w = fmaf(S.w, Wg[I].w, fmaf(sa, Bg[I].w, cv * Kg[I].w)); \
    const float q = fmaf(S.y, Rg[I].y, S.x * Rg[I].x) + fmaf(S.w, Rg[I].w, S.z * Rg[I].z); \
    const float oo = red16(q); \
    oreg = (L == (SIDX)) ? oo : oreg; }

#define VMW(N) asm volatile("s_waitcnt vmcnt(" #N ")" ::: "memory");

  // prologue: slots 0..7 <- steps 0..7; prime sets 0-3; refill slots 0-3 <- 8..11
  G2L6(0) G2L6(1) G2L6(2) G2L6(3) G2L6(4) G2L6(5) G2L6(6) G2L6(7)
  VMW(24)
  PREF(0,0) PREF(1,1) PREF(2,2) PREF(3,3)
  G2L6(0) G2L6(1) G2L6(2) G2L6(3)

  for (int tile = 0; tile < TSEQ/16; ++tile){
    VMW(24)
    PREF(4,4) PREF(5,5) PREF(6,6) PREF(7,7)
    STEP(0,0) STEP(1,1) STEP(2,2) STEP(3,3)
    G2L6(4) G2L6(5) G2L6(6) G2L6(7)
    VMW(24)
    PREF(0,0) PREF(1,1) PREF(2,2) PREF(3,3)
    STEP(4,4) STEP(5,5) STEP(6,6) STEP(7,7)
    G2L6(0) G2L6(1) G2L6(2) G2L6(3)
    VMW(24)
    PREF(4,4) PREF(5,5) PREF(6,6) PREF(7,7)
    STEP(0,8) STEP(1,9) STEP(2,10) STEP(3,11)
    G2L6(4) G2L6(5) G2L6(6) G2L6(7)
    VMW(24)
    PREF(0,0) PREF(1,1) PREF(2,2) PREF(3,3)
    STEP(4,12) STEP(5,13) STEP(6,14) STEP(7,15)
    G2L6(0) G2L6(1) G2L6(2) G2L6(3)
    o[base + (size_t)(tile*16 + L) * 1024 + vrow] = oreg;   // 1 store / 16 steps
  }

#undef G2L6
#undef PREF
#undef STEP
#undef VMW
}

// ---------------- GroupNorm + bonus + gate -> y (bf16) ----------------
__global__ __launch_bounds__(256) void gnout_k(
    const float* __restrict__ o, const float* __restrict__ r, const float* __restrict__ k,
    const float* __restrict__ v, const float* __restrict__ g,
    const float* __restrict__ rk, const float* __restrict__ gnw, const float* __restrict__ gnb,
    unsigned short* __restrict__ y)
{
  const int row  = blockIdx.x * 4 + (threadIdx.x >> 6);
  const int lane = threadIdx.x & 63;
  const size_t idx = (size_t)row * 64 + lane;
  const int c = ((row & 15) << 6) + lane;
  const float ov  = o[idx];
  const float mu  = wredsum(ov) * 0.015625f;
  const float d   = ov - mu;
  const float var = wredsum(d * d) * 0.015625f;
  const float on  = d * rsqrtf(var + 6.4e-4f) * gnw[c] + gnb[c];   // eps = D*1e-5
  const float s   = wredsum(r[idx] * k[idx] * rk[c]);
  const float yv  = (on + s * v[idx]) * g[idx];
  y[idx] = f2bf(yv);
}

extern "C" void kernel_launch(void* const* d_in, const int* in_sizes, int n_in,
                              void* d_out, int out_size, void* d_ws, size_t ws_size,
                              hipStream_t stream)
{
  const float* x    = (const float*)d_in[0];
  const float* x_r  = (const float*)d_in[1];
  const float* x_w  = (const float*)d_in[2];
  const float* x_k  = (const float*)d_in[3];
  const float* x_v  = (const float*)d_in[4];
  const float* x_a  = (const float*)d_in[5];
  const float* x_g  = (const float*)d_in[6];
  const float* k_k  = (const float*)d_in[7];
  const float* k_a  = (const float*)d_in[8];
  const float* r_k  = (const float*)d_in[9];
  const float* Wr   = (const float*)d_in[10];
  const float* Wk   = (const float*)d_in[11];
  const float* Wv   = (const float*)d_in[12];
  const float* Wo   = (const float*)d_in[13];
  const float* wA   = (const float*)d_in[14];
  const float* wB   = (const float*)d_in[15];
  const float* wbias= (const float*)d_in[16];
  const float* aA   = (const float*)d_in[17];
  const float* aB   = (const float*)d_in[18];
  const float* abias= (const float*)d_in[19];
  const float* gA   = (const float*)d_in[20];
  const float* gB   = (const float*)d_in[21];
  const float* gnw  = (const float*)d_in[22];
  const float* gnb  = (const float*)d_in[23];
  const float* w0b  = (const float*)d_in[24];
  const float* w0d  = (const float*)d_in[25];

  char* ws = (char*)d_ws;
  const size_t MB = 1024ull * 1024ull;
  const size_t KB = 1024ull;
  float* r_  = (float*)(ws +   0*MB);
  float* k_  = (float*)(ws +  16*MB);
  float* v_  = (float*)(ws +  32*MB);
  float* wd_ = (float*)(ws +  48*MB);   // decay (overlaps dead xk_)
  float* ab_ = (float*)(ws +  64*MB);   // a, then b (in place)
  float* kk_ = (float*)(ws +  80*MB);   // (overlaps dead xa_/xg_)
  float* o_  = (float*)(ws +  96*MB);   // (overlaps dead xv_/xw_)
  float* g_  = (float*)(ws + 112*MB);
  unsigned short* y_   = (unsigned short*)(ws + 128*MB);   // (overlaps dead xr_)
  unsigned short* wl1_ = (unsigned short*)(ws + 136*MB);
  unsigned short* al1_ = (unsigned short*)(ws + 136*MB + 512*KB);
  unsigned short* gl1_ = (unsigned short*)(ws + 137*MB);
  float*          w0_  = (float*)(ws + 138*MB + 512*KB);
  unsigned short* wbf_ = (unsigned short*)(ws + 139*MB);   // all weights bf16 (~9.6MB)
  // mixed bf16 inputs (8MB each), carved from regions written later:
  unsigned short* xr_ = (unsigned short*)(ws + 128*MB);    // dead before y_ write
  unsigned short* xw_ = (unsigned short*)(ws + 104*MB);    // dead before o_ write
  unsigned short* xk_ = (unsigned short*)(ws +  48*MB);    // dead before wd_ write
  unsigned short* xv_ = (unsigned short*)(ws +  96*MB);    // dead before o_ write
  unsigned short* xa_ = (unsigned short*)(ws +  80*MB);    // dead before kk_ write
  unsigned short* xg_ = (unsigned short*)(ws +  88*MB);    // dead before kk_ write

  // bf16 weight offsets (elements)
  const unsigned short* bWr = wbf_ + 0;
  const unsigned short* bWk = wbf_ + 1048576;
  const unsigned short* bWv = wbf_ + 2097152;
  const unsigned short* bWo = wbf_ + 3145728;
  const unsigned short* bwA = wbf_ + 4194304;
  const unsigned short* bwB = wbf_ + 4259840;
  const unsigned short* baA = wbf_ + 4325376;
  const unsigned short* baB = wbf_ + 4390912;
  const unsigned short* bgA = wbf_ + 4456448;
  const unsigned short* bgB = wbf_ + 4620288;

  const dim3 blk(256);
  const dim3 gBig(8, 32), gN64(1, 32), gN160(2, 32);

  w0_scan_k<<<dim3(1), dim3(1024), 0, stream>>>(w0b, w0d, w0_);

  WCvtArgs wargs;
  wargs.src[0]=Wr; wargs.src[1]=Wk; wargs.src[2]=Wv; wargs.src[3]=Wo;
  wargs.src[4]=wA; wargs.src[5]=wB; wargs.src[6]=aA; wargs.src[7]=aB;
  wargs.src[8]=gA; wargs.src[9]=gB;
  wcvt_k<<<dim3(WTOT/4/256), blk, 0, stream>>>(wargs, wbf_);

  prep_k<<<dim3(4096), blk, 0, stream>>>(x, x_r, x_w, x_k, x_v, x_a, x_g,
                                         xr_, xw_, xk_, xv_, xa_, xg_);

  // r, k, v projections
  gemm_k<EPI_F32><<<gBig, blk, 0, stream>>>(xr_, bWr, r_, nullptr, nullptr, 4096, 1024, 1024);
  gemm_k<EPI_F32><<<gBig, blk, 0, stream>>>(xk_, bWk, k_, nullptr, nullptr, 4096, 1024, 1024);
  gemm_k<EPI_F32><<<gBig, blk, 0, stream>>>(xv_, bWv, v_, nullptr, nullptr, 4096, 1024, 1024);

  // decay LoRA: tanh(xw@A^T) -> @B^T + bias + w0 -> decay
  gemm_k<EPI_TANH_BF16><<<gN64, blk, 0, stream>>>(xw_, bwA, wl1_, nullptr, nullptr, 4096, 64, 1024);
  gemm_k<EPI_DECAY_F32><<<gBig, blk, 0, stream>>>(wl1_, bwB, wd_, wbias, w0_, 4096, 1024, 64);

  // a LoRA: (xa@A^T) -> sigmoid(@B^T + bias)
  gemm_k<EPI_BF16><<<gN64, blk, 0, stream>>>(xa_, baA, al1_, nullptr, nullptr, 4096, 64, 1024);
  gemm_k<EPI_SIGBIAS_F32><<<gBig, blk, 0, stream>>>(al1_, baB, ab_, abias, nullptr, 4096, 1024, 64);

  // g LoRA: sigmoid(xg@A^T) -> @B^T
  gemm_k<EPI_SIG_BF16><<<gN160, blk, 0, stream>>>(xg_, bgA, gl1_, nullptr, nullptr, 4096, 160, 1024);
  gemm_k<EPI_F32><<<gBig, blk, 0, stream>>>(gl1_, bgB, g_, nullptr, nullptr, 4096, 1024, 160);

  // kk normalize (negated) + k scale + b
  kkprep_k<<<dim3(16384), blk, 0, stream>>>(k_, ab_, kk_, k_k, k_a);

  // sequential recurrence (LDS-ring, 4-step regions, batched stores)
  scan_k<<<dim3(512), dim3(64), 0, stream>>>(r_, wd_, k_, v_, ab_, kk_, o_);

  // GroupNorm + bonus + gate
  gnout_k<<<dim3(16384), blk, 0, stream>>>(o_, r_, k_, v_, g_, r_k, gnw, gnb, y_);

  // output projection
  gemm_k<EPI_F32><<<gBig, blk, 0, stream>>>(y_, bWo, (float*)d_out, nullptr, nullptr, 4096, 1024, 1024);
}

// Round 12
// 490.753 us; speedup vs baseline: 1.1788x; 1.1786x over previous
//
#include <hip/hip_runtime.h>
#include <hip/hip_bf16.h>
#include <math.h>

typedef float f32x4 __attribute__((ext_vector_type(4)));
typedef short s16x8 __attribute__((ext_vector_type(8)));
typedef short s16x4 __attribute__((ext_vector_type(4)));

#define TSEQ 2048

__device__ __forceinline__ unsigned short f2bf(float f){
  unsigned int u = __builtin_bit_cast(unsigned int, f);
  u += 0x7FFFu + ((u >> 16) & 1u);
  return (unsigned short)(u >> 16);
}
__device__ __forceinline__ float sigf(float x){ return 1.0f / (1.0f + __expf(-x)); }
__device__ __forceinline__ float wredsum(float x){
  #pragma unroll
  for (int off = 32; off > 0; off >>= 1) x += __shfl_xor(x, off);
  return x;
}

// 16-lane-group sum via DPP — no LDS.
template<int CTRL>
__device__ __forceinline__ float dpp_add(float x){
  int v = __builtin_amdgcn_update_dpp(0, __builtin_bit_cast(int, x), CTRL, 0xF, 0xF, true);
  return x + __builtin_bit_cast(float, v);
}
__device__ __forceinline__ float red16(float x){
  x = dpp_add<0xB1>(x);   // quad_perm [1,0,3,2]
  x = dpp_add<0x4E>(x);   // quad_perm [2,3,0,1]
  x = dpp_add<0x124>(x);  // row_ror:4
  x = dpp_add<0x128>(x);  // row_ror:8
  return x;
}

// async global->LDS, 16B per lane: dest = uniform base + lane*16, src per-lane.
__device__ __forceinline__ void g2l16(const unsigned short* gp, void* lp){
  __builtin_amdgcn_global_load_lds(
    (const __attribute__((address_space(1))) unsigned int*)gp,
    (__attribute__((address_space(3))) unsigned int*)lp, 16, 0, 0);
}
__device__ __forceinline__ void g2l16f(const float* gp, void* lp){
  __builtin_amdgcn_global_load_lds(
    (const __attribute__((address_space(1))) unsigned int*)gp,
    (__attribute__((address_space(3))) unsigned int*)lp, 16, 0, 0);
}

// ---------------- w0 prefix-scan (C=1024) ----------------
__global__ void w0_scan_k(const float* __restrict__ w0b, const float* __restrict__ w0d,
                          float* __restrict__ w0){
  __shared__ float buf[1024];
  int i = threadIdx.x;
  float v = 0.f;
  if (i > 0){
    float d = w0d[i-1];
    v = (d > 20.f) ? d : log1pf(__expf(d));   // softplus
  }
  buf[i] = v;
  __syncthreads();
  for (int off = 1; off < 1024; off <<= 1){
    float t = (i >= off) ? buf[i - off] : 0.f;
    __syncthreads();
    buf[i] += t;
    __syncthreads();
  }
  w0[i] = w0b[0] + buf[i];
}

// ---------------- convert all weights f32 -> bf16 (once) ----------------
struct WCvtArgs { const float* src[10]; };
__constant__ const int WCSUM[11] = {0, 1048576, 2097152, 3145728, 4194304,
                                    4259840, 4325376, 4390912, 4456448, 4620288, 4784128};
#define WTOT 4784128

__global__ __launch_bounds__(256) void wcvt_k(WCvtArgs args, unsigned short* __restrict__ dst){
  const int e0 = (blockIdx.x * 256 + threadIdx.x) * 4;
  #pragma unroll
  for (int i = 0; i < 10; i++){
    if (e0 < WCSUM[i+1]){
      const f32x4 q = *(const f32x4*)(args.src[i] + (e0 - WCSUM[i]));
      s16x4 o; o[0]=(short)f2bf(q.x); o[1]=(short)f2bf(q.y); o[2]=(short)f2bf(q.z); o[3]=(short)f2bf(q.w);
      *(s16x4*)(dst + e0) = o;
      return;
    }
  }
}

// ---------------- token-shift mix -> 6 bf16 arrays (once) ----------------
__global__ __launch_bounds__(256) void prep_k(
    const float* __restrict__ x,
    const float* __restrict__ cr, const float* __restrict__ cw, const float* __restrict__ ck,
    const float* __restrict__ cv, const float* __restrict__ ca, const float* __restrict__ cg,
    unsigned short* __restrict__ xr, unsigned short* __restrict__ xw, unsigned short* __restrict__ xk,
    unsigned short* __restrict__ xv, unsigned short* __restrict__ xa, unsigned short* __restrict__ xg)
{
  const int m = blockIdx.x;
  const int c = threadIdx.x * 4;
  const size_t ix = (size_t)m * 1024 + c;
  const f32x4 q = *(const f32x4*)(x + ix);
  f32x4 s = {0.f,0.f,0.f,0.f};
  if ((m & (TSEQ - 1)) != 0) s = *(const f32x4*)(x + ix - 1024);
  const f32x4 d = s - q;
  #define DO_MIX(coef, out) { \
    const f32x4 mc = *(const f32x4*)(coef + c); \
    s16x4 o; \
    o[0]=(short)f2bf(fmaf(d.x, mc.x, q.x)); o[1]=(short)f2bf(fmaf(d.y, mc.y, q.y)); \
    o[2]=(short)f2bf(fmaf(d.z, mc.z, q.z)); o[3]=(short)f2bf(fmaf(d.w, mc.w, q.w)); \
    *(s16x4*)(out + ix) = o; }
  DO_MIX(cr, xr); DO_MIX(cw, xw); DO_MIX(ck, xk);
  DO_MIX(cv, xv); DO_MIX(ca, xa); DO_MIX(cg, xg);
  #undef DO_MIX
}

// ---------------- bf16 MFMA GEMM, global_load_lds + double buffer ----------------
#define EPI_F32 0
#define EPI_BF16 1
#define EPI_TANH_BF16 2
#define EPI_SIG_BF16 3
#define EPI_PK_F32 4
#define EPI_PK_SIG 5
#define EPI_PK_DECAY 6

template<int EPI, int ARR>
__global__ __launch_bounds__(256) void gemm_k(
    const unsigned short* __restrict__ ABF,    // (M,K) bf16
    const unsigned short* __restrict__ BBF,    // (N,K) bf16
    void* __restrict__ Cout,
    const float* __restrict__ bias, const float* __restrict__ w0,
    int M, int N, int K)
{
  __shared__ unsigned short As[2][128][32];
  __shared__ unsigned short Bs[2][128][32];
  const int tid  = threadIdx.x;
  const int m0   = blockIdx.y * 128;
  const int n0   = blockIdx.x * 128;
  const int srow = tid >> 2;
  const int scol = (tid & 3) << 3;
  const int wofs = (tid >> 6) << 10;
  const int lane = tid & 63;
  const int wv   = tid >> 6;
  const int wr   = (wv >> 1) << 6;
  const int wc   = (wv & 1) << 6;
  const int lr   = lane & 15;
  const int lg   = lane >> 4;

#define STAGE(BUF, KOFF) { \
    const unsigned short* a0 = ABF + (size_t)(m0 + srow) * K + (KOFF) + scol; \
    const unsigned short* b0 = BBF + (size_t)(n0 + srow) * K + (KOFF) + scol; \
    g2l16(a0,                 (char*)&As[BUF][0][0] + wofs); \
    g2l16(a0 + (size_t)64*K,  (char*)&As[BUF][0][0] + 4096 + wofs); \
    g2l16(b0,                 (char*)&Bs[BUF][0][0] + wofs); \
    g2l16(b0 + (size_t)64*K,  (char*)&Bs[BUF][0][0] + 4096 + wofs); }

  f32x4 acc[4][4];
  #pragma unroll
  for (int i = 0; i < 4; i++)
    #pragma unroll
    for (int j = 0; j < 4; j++) acc[i][j] = f32x4{0.f, 0.f, 0.f, 0.f};

  STAGE(0, 0)
  __syncthreads();

  int buf = 0;
  for (int k0 = 0; k0 < K; k0 += 32){
    if (k0 + 32 < K){ STAGE(buf ^ 1, k0 + 32) }
    s16x8 af[4], bfr[4];
    #pragma unroll
    for (int i = 0; i < 4; i++) af[i]  = *(const s16x8*)&As[buf][wr + i*16 + lr][lg*8];
    #pragma unroll
    for (int j = 0; j < 4; j++) bfr[j] = *(const s16x8*)&Bs[buf][wc + j*16 + lr][lg*8];
    #pragma unroll
    for (int i = 0; i < 4; i++)
      #pragma unroll
      for (int j = 0; j < 4; j++)
        acc[i][j] = __builtin_amdgcn_mfma_f32_16x16x32_bf16(af[i], bfr[j], acc[i][j], 0, 0, 0);
    __syncthreads();
    buf ^= 1;
  }
#undef STAGE

  #pragma unroll
  for (int i = 0; i < 4; i++){
    const int mb = m0 + wr + i*16 + lg*4;
    #pragma unroll
    for (int j = 0; j < 4; j++){
      const int n = n0 + wc + j*16 + lr;
      if (n < N){
        #pragma unroll
        for (int q = 0; q < 4; q++){
          const int m = mb + q;
          const float val = acc[i][j][q];
          if constexpr (EPI == EPI_PK_F32 || EPI == EPI_PK_SIG || EPI == EPI_PK_DECAY){
            // packed dest: pk[(b*16+h)][t][ARR*64+ch]
            const int b2 = m >> 11, t2 = m & 2047, h2 = n >> 6, ch = n & 63;
            const size_t pix = (size_t)(b2*16 + h2) * (TSEQ*384) + (size_t)t2*384 + ARR*64 + ch;
            if constexpr (EPI == EPI_PK_F32) ((float*)Cout)[pix] = val;
            else if constexpr (EPI == EPI_PK_SIG) ((float*)Cout)[pix] = sigf(val + bias[n]);
            else {
              float z = val + bias[n] + w0[n];
              ((float*)Cout)[pix] = expf(-0.60653065971263342f * sigf(z));
            }
          } else {
            const size_t oix = (size_t)m * N + n;
            if constexpr (EPI == EPI_F32)            ((float*)Cout)[oix] = val;
            else if constexpr (EPI == EPI_BF16)      ((unsigned short*)Cout)[oix] = f2bf(val);
            else if constexpr (EPI == EPI_TANH_BF16) ((unsigned short*)Cout)[oix] = f2bf(tanhf(val));
            else if constexpr (EPI == EPI_SIG_BF16)  ((unsigned short*)Cout)[oix] = f2bf(sigf(val));
          }
        }
      }
    }
  }
}

// ---------------- kk normalize (in pk): k_raw,a_raw -> k_scaled, b, -kk ----------------
__global__ __launch_bounds__(256) void kkprep2_k(
    float* __restrict__ pk, const float* __restrict__ kkc, const float* __restrict__ kac)
{
  const int flat = blockIdx.x * 4 + (threadIdx.x >> 6);   // (bh, t)
  const int lane = threadIdx.x & 63;
  const int bh = flat >> 11, t = flat & 2047;
  const size_t pb = (size_t)bh * (TSEQ*384) + (size_t)t * 384;
  const int c = (bh & 15) * 64 + lane;
  const float kraw = pk[pb + 128 + lane];
  const float araw = pk[pb + 192 + lane];
  const float tt = kraw * kkc[c];
  const float ss = wredsum(tt * tt);
  const float kkv = tt / fmaxf(sqrtf(ss), 1e-12f);
  pk[pb + 128 + lane] = kraw * (1.f + (araw - 1.f) * kac[c]);
  pk[pb + 192 + lane] = kkv * araw;     // b_in
  pk[pb + 256 + lane] = -kkv;           // a_in (pre-negated)
}

// ---------------- RWKV-7 scan: packed stream, ring-32, XCD-local siblings ----------
// pk[bh][t][384] = [r|w|k|b|-kk|v], 1536B/step. Ring = 8 groups x 4 steps (48KB LDS,
// 48 loads in flight, 6 g2l16 per group). Wait distance = 7 groups = 28 steps.
// Block swizzle: blockIdx%8 == bh%8 so all 16 row-group siblings of one bh share
// an XCD -> redundant reads are L2 hits. o -> separate flat buffer (sibling-safe).
__global__ __launch_bounds__(64) void scan_k(
    const float* __restrict__ pk, float* __restrict__ o)
{
  const int lane = threadIdx.x;
  const int L = lane & 15, g = lane >> 4;
  const int f = blockIdx.x;
  const int grp = (f >> 3) & 15;
  const int bh  = ((f >> 7) << 3) | (f & 7);
  const int b_  = bh >> 4, h_ = bh & 15;
  const size_t pkb = (size_t)bh * (TSEQ * 384);
  const int vq = 4 * L;
  const int vrow = grp * 4 + g;

  __shared__ float lds[8][1536];    // 48 KB
  int mload = 0;                    // next group to load

#define G2LG(SLOT) { \
    const int mc = (mload < TSEQ/4) ? mload : (TSEQ/4 - 1); \
    const float* src = pk + pkb + (size_t)mc * 1536 + lane * 4; \
    g2l16f(src +    0, &lds[SLOT][0]);    \
    g2l16f(src +  256, &lds[SLOT][256]);  \
    g2l16f(src +  512, &lds[SLOT][512]);  \
    g2l16f(src +  768, &lds[SLOT][768]);  \
    g2l16f(src + 1024, &lds[SLOT][1024]); \
    g2l16f(src + 1280, &lds[SLOT][1280]); \
    mload++; }

  f32x4 Rg[8], Wg[8], Kg[8], Bg[8], Ag[8]; float Vg[8];

#define PREF1(SLOT, I, SET) { \
    const float* pb_ = &lds[SLOT][(I)*384]; \
    Rg[SET] = *(const f32x4*)(pb_ + vq); \
    Wg[SET] = *(const f32x4*)(pb_ + 64 + vq); \
    Kg[SET] = *(const f32x4*)(pb_ + 128 + vq); \
    Bg[SET] = *(const f32x4*)(pb_ + 192 + vq); \
    Ag[SET] = *(const f32x4*)(pb_ + 256 + vq); \
    Vg[SET] = pb_[320 + vrow]; }
#define PREF4(SLOT, SB) PREF1(SLOT,0,SB+0) PREF1(SLOT,1,SB+1) PREF1(SLOT,2,SB+2) PREF1(SLOT,3,SB+3)

  f32x4 S = {0.f, 0.f, 0.f, 0.f};
  float oreg = 0.f;

#define STEP(I, SIDX) { \
    const float p = fmaf(S.y, Ag[I].y, S.x * Ag[I].x) + fmaf(S.w, Ag[I].w, S.z * Ag[I].z); \
    const float sa = red16(p); \
    const float cv = Vg[I]; \
    S.x = fmaf(S.x, Wg[I].x, fmaf(sa, Bg[I].x, cv * Kg[I].x)); \
    S.y = fmaf(S.y, Wg[I].y, fmaf(sa, Bg[I].y, cv * Kg[I].y)); \
    S.z = fmaf(S.z, Wg[I].z, fmaf(sa, Bg[I].z, cv * Kg[I].z)); \
    S.w = fmaf(S.w, Wg[I].w, fmaf(sa, Bg[I].w, cv * Kg[I].w)); \
    const float q = fmaf(S.y, Rg[I].y, S.x * Rg[I].x) + fmaf(S.w, Rg[I].w, S.z * Rg[I].z); \
    const float oo = red16(q); \
    oreg = (L == (SIDX)) ? oo : oreg; }

#define VMW(N) asm volatile("s_waitcnt vmcnt(" #N ")" ::: "memory");

  // Per seq J: wait group landed -> PREF next slot -> STEP current sets -> refill.
#define SEQ(J, PSET, CSET) \
    VMW(36) \
    PREF4((J+1)&7, PSET) \
    STEP(CSET+0, ((J)&3)*4+0) STEP(CSET+1, ((J)&3)*4+1) \
    STEP(CSET+2, ((J)&3)*4+2) STEP(CSET+3, ((J)&3)*4+3) \
    G2LG(J)

  // prologue: groups 0..7, prime sets A with group 0
  G2LG(0) G2LG(1) G2LG(2) G2LG(3) G2LG(4) G2LG(5) G2LG(6) G2LG(7)
  VMW(42)
  PREF4(0, 0)

  const size_t ob = (size_t)b_ * (TSEQ*1024) + h_*64;
  for (int ot = 0; ot < TSEQ/32; ++ot){
    SEQ(0,4,0) SEQ(1,0,4) SEQ(2,4,0) SEQ(3,0,4)
    o[ob + (size_t)(32*ot + L) * 1024 + vrow] = oreg;        // steps 32ot..+15
    SEQ(4,4,0) SEQ(5,0,4) SEQ(6,4,0) SEQ(7,0,4)
    o[ob + (size_t)(32*ot + 16 + L) * 1024 + vrow] = oreg;   // steps 32ot+16..+31
  }

#undef G2LG
#undef PREF1
#undef PREF4
#undef STEP
#undef VMW
#undef SEQ
}

// ---------------- GroupNorm + bonus + gate -> y (bf16) ----------------
__global__ __launch_bounds__(256) void gnout_k(
    const float* __restrict__ pk, const float* __restrict__ o, const float* __restrict__ g_,
    const float* __restrict__ rk, const float* __restrict__ gnw, const float* __restrict__ gnb,
    unsigned short* __restrict__ y)
{
  const int flat = blockIdx.x * 4 + (threadIdx.x >> 6);  // (bh, t)
  const int lane = threadIdx.x & 63;
  const int bh = flat >> 11, t = flat & 2047;
  const int b_ = bh >> 4, h_ = bh & 15;
  const size_t pb = (size_t)bh * (TSEQ*384) + (size_t)t * 384;
  const int c = h_*64 + lane;
  const size_t fi = (size_t)(b_*2048 + t) * 1024 + c;
  const float rv = pk[pb + lane];
  const float kv = pk[pb + 128 + lane];
  const float vv = pk[pb + 320 + lane];
  const float ov = o[fi];
  const float mu  = wredsum(ov) * 0.015625f;
  const float d   = ov - mu;
  const float var = wredsum(d * d) * 0.015625f;
  const float on  = d * rsqrtf(var + 6.4e-4f) * gnw[c] + gnb[c];   // eps = D*1e-5
  const float s   = wredsum(rv * kv * rk[c]);
  const float yv  = (on + s * vv) * g_[fi];
  y[fi] = f2bf(yv);
}

extern "C" void kernel_launch(void* const* d_in, const int* in_sizes, int n_in,
                              void* d_out, int out_size, void* d_ws, size_t ws_size,
                              hipStream_t stream)
{
  const float* x    = (const float*)d_in[0];
  const float* x_r  = (const float*)d_in[1];
  const float* x_w  = (const float*)d_in[2];
  const float* x_k  = (const float*)d_in[3];
  const float* x_v  = (const float*)d_in[4];
  const float* x_a  = (const float*)d_in[5];
  const float* x_g  = (const float*)d_in[6];
  const float* k_k  = (const float*)d_in[7];
  const float* k_a  = (const float*)d_in[8];
  const float* r_k  = (const float*)d_in[9];
  const float* Wr   = (const float*)d_in[10];
  const float* Wk   = (const float*)d_in[11];
  const float* Wv   = (const float*)d_in[12];
  const float* Wo   = (const float*)d_in[13];
  const float* wA   = (const float*)d_in[14];
  const float* wB   = (const float*)d_in[15];
  const float* wbias= (const float*)d_in[16];
  const float* aA   = (const float*)d_in[17];
  const float* aB   = (const float*)d_in[18];
  const float* abias= (const float*)d_in[19];
  const float* gA   = (const float*)d_in[20];
  const float* gB   = (const float*)d_in[21];
  const float* gnw  = (const float*)d_in[22];
  const float* gnb  = (const float*)d_in[23];
  const float* w0b  = (const float*)d_in[24];
  const float* w0d  = (const float*)d_in[25];

  char* ws = (char*)d_ws;
  const size_t MB = 1024ull * 1024ull;
  const size_t KB = 1024ull;

  // Memory plan (max 149 MB):
  float*          pk_  = (float*)(ws + 0);                 // 0..96MB packed [r|w|k|b|-kk|v]
  unsigned short* xw_  = (unsigned short*)(ws + 0*MB);     // in pk, dead before pk writes
  unsigned short* xa_  = (unsigned short*)(ws + 8*MB);     // in pk
  unsigned short* xg_  = (unsigned short*)(ws + 16*MB);    // in pk
  float*          g_   = (float*)(ws + 96*MB);             // 96..112
  unsigned short* xr_  = (unsigned short*)(ws + 96*MB);    // in g_, dead before g_ write
  unsigned short* xk_  = (unsigned short*)(ws + 104*MB);   // in g_
  unsigned short* y_   = (unsigned short*)(ws + 112*MB);   // 112..120
  unsigned short* xv_  = (unsigned short*)(ws + 112*MB);   // in y_, dead before y write
  unsigned short* wbf_ = (unsigned short*)(ws + 120*MB);   // 120..130 (9.6MB)
  unsigned short* wl1_ = (unsigned short*)(ws + 130*MB);
  unsigned short* al1_ = (unsigned short*)(ws + 130*MB + 512*KB);
  unsigned short* gl1_ = (unsigned short*)(ws + 131*MB);   // 1.25MB
  float*          w0_  = (float*)(ws + 132*MB + 512*KB);
  float*          o_   = (float*)(ws + 133*MB);            // 133..149

  const unsigned short* bWr = wbf_ + 0;
  const unsigned short* bWk = wbf_ + 1048576;
  const unsigned short* bWv = wbf_ + 2097152;
  const unsigned short* bWo = wbf_ + 3145728;
  const unsigned short* bwA = wbf_ + 4194304;
  const unsigned short* bwB = wbf_ + 4259840;
  const unsigned short* baA = wbf_ + 4325376;
  const unsigned short* baB = wbf_ + 4390912;
  const unsigned short* bgA = wbf_ + 4456448;
  const unsigned short* bgB = wbf_ + 4620288;

  const dim3 blk(256);
  const dim3 gBig(8, 32), gN64(1, 32), gN160(2, 32);

  w0_scan_k<<<dim3(1), dim3(1024), 0, stream>>>(w0b, w0d, w0_);

  WCvtArgs wargs;
  wargs.src[0]=Wr; wargs.src[1]=Wk; wargs.src[2]=Wv; wargs.src[3]=Wo;
  wargs.src[4]=wA; wargs.src[5]=wB; wargs.src[6]=aA; wargs.src[7]=aB;
  wargs.src[8]=gA; wargs.src[9]=gB;
  wcvt_k<<<dim3(WTOT/4/256), blk, 0, stream>>>(wargs, wbf_);

  prep_k<<<dim3(4096), blk, 0, stream>>>(x, x_r, x_w, x_k, x_v, x_a, x_g,
                                         xr_, xw_, xk_, xv_, xa_, xg_);

  // LoRA stage-1 first (xw/xa/xg die before pk is written)
  gemm_k<EPI_TANH_BF16,0><<<gN64, blk, 0, stream>>>(xw_, bwA, wl1_, nullptr, nullptr, 4096, 64, 1024);
  gemm_k<EPI_BF16,0><<<gN64, blk, 0, stream>>>(xa_, baA, al1_, nullptr, nullptr, 4096, 64, 1024);
  gemm_k<EPI_SIG_BF16,0><<<gN160, blk, 0, stream>>>(xg_, bgA, gl1_, nullptr, nullptr, 4096, 160, 1024);

  // projections -> pk slots
  gemm_k<EPI_PK_F32,0><<<gBig, blk, 0, stream>>>(xr_, bWr, pk_, nullptr, nullptr, 4096, 1024, 1024);
  gemm_k<EPI_PK_F32,2><<<gBig, blk, 0, stream>>>(xk_, bWk, pk_, nullptr, nullptr, 4096, 1024, 1024);
  gemm_k<EPI_PK_F32,5><<<gBig, blk, 0, stream>>>(xv_, bWv, pk_, nullptr, nullptr, 4096, 1024, 1024);

  // LoRA stage-2 -> pk slots (decay into arr1, raw a into arr3)
  gemm_k<EPI_PK_DECAY,1><<<gBig, blk, 0, stream>>>(wl1_, bwB, pk_, wbias, w0_, 4096, 1024, 64);
  gemm_k<EPI_PK_SIG,3><<<gBig, blk, 0, stream>>>(al1_, baB, pk_, abias, nullptr, 4096, 1024, 64);

  // gate -> flat g_
  gemm_k<EPI_F32,0><<<gBig, blk, 0, stream>>>(gl1_, bgB, g_, nullptr, nullptr, 4096, 1024, 160);

  // k/b/kk finalize inside pk
  kkprep2_k<<<dim3(16384), blk, 0, stream>>>(pk_, k_k, k_a);

  // sequential recurrence (packed stream, ring-32, XCD-local)
  scan_k<<<dim3(512), dim3(64), 0, stream>>>(pk_, o_);

  // GroupNorm + bonus + gate
  gnout_k<<<dim3(16384), blk, 0, stream>>>(pk_, o_, g_, r_k, gnw, gnb, y_);

  // output projection
  gemm_k<EPI_F32,0><<<gBig, blk, 0, stream>>>(y_, bWo, (float*)d_out, nullptr, nullptr, 4096, 1024, 1024);
}

// Round 14
// 449.729 us; speedup vs baseline: 1.2864x; 1.0912x over previous
//
#include <hip/hip_runtime.h>
#include <hip/hip_bf16.h>
#include <math.h>

typedef float f32x4 __attribute__((ext_vector_type(4)));
typedef short s16x8 __attribute__((ext_vector_type(8)));
typedef short s16x4 __attribute__((ext_vector_type(4)));

#define TSEQ 2048

__device__ __forceinline__ unsigned short f2bf(float f){
  unsigned int u = __builtin_bit_cast(unsigned int, f);
  u += 0x7FFFu + ((u >> 16) & 1u);
  return (unsigned short)(u >> 16);
}
__device__ __forceinline__ float sigf(float x){ return 1.0f / (1.0f + __expf(-x)); }
__device__ __forceinline__ float wredsum(float x){
  #pragma unroll
  for (int off = 32; off > 0; off >>= 1) x += __shfl_xor(x, off);
  return x;
}

// 16-lane-group sum via DPP — no LDS.
template<int CTRL>
__device__ __forceinline__ float dpp_add(float x){
  int v = __builtin_amdgcn_update_dpp(0, __builtin_bit_cast(int, x), CTRL, 0xF, 0xF, true);
  return x + __builtin_bit_cast(float, v);
}
__device__ __forceinline__ float red16(float x){
  x = dpp_add<0xB1>(x);   // quad_perm [1,0,3,2]
  x = dpp_add<0x4E>(x);   // quad_perm [2,3,0,1]
  x = dpp_add<0x124>(x);  // row_ror:4
  x = dpp_add<0x128>(x);  // row_ror:8
  return x;
}

// async global->LDS, 16B per lane: dest = uniform base + lane*16, src per-lane.
__device__ __forceinline__ void g2l16(const unsigned short* gp, void* lp){
  __builtin_amdgcn_global_load_lds(
    (const __attribute__((address_space(1))) unsigned int*)gp,
    (__attribute__((address_space(3))) unsigned int*)lp, 16, 0, 0);
}
__device__ __forceinline__ void g2l16f(const float* gp, void* lp){
  __builtin_amdgcn_global_load_lds(
    (const __attribute__((address_space(1))) unsigned int*)gp,
    (__attribute__((address_space(3))) unsigned int*)lp, 16, 0, 0);
}

// ---------------- w0 prefix-scan (C=1024) ----------------
__global__ void w0_scan_k(const float* __restrict__ w0b, const float* __restrict__ w0d,
                          float* __restrict__ w0){
  __shared__ float buf[1024];
  int i = threadIdx.x;
  float v = 0.f;
  if (i > 0){
    float d = w0d[i-1];
    v = (d > 20.f) ? d : log1pf(__expf(d));   // softplus
  }
  buf[i] = v;
  __syncthreads();
  for (int off = 1; off < 1024; off <<= 1){
    float t = (i >= off) ? buf[i - off] : 0.f;
    __syncthreads();
    buf[i] += t;
    __syncthreads();
  }
  w0[i] = w0b[0] + buf[i];
}

// ---------------- convert all weights f32 -> bf16 (once) ----------------
struct WCvtArgs { const float* src[10]; };
__constant__ const int WCSUM[11] = {0, 1048576, 2097152, 3145728, 4194304,
                                    4259840, 4325376, 4390912, 4456448, 4620288, 4784128};
#define WTOT 4784128

__global__ __launch_bounds__(256) void wcvt_k(WCvtArgs args, unsigned short* __restrict__ dst){
  const int e0 = (blockIdx.x * 256 + threadIdx.x) * 4;
  #pragma unroll
  for (int i = 0; i < 10; i++){
    if (e0 < WCSUM[i+1]){
      const f32x4 q = *(const f32x4*)(args.src[i] + (e0 - WCSUM[i]));
      s16x4 o; o[0]=(short)f2bf(q.x); o[1]=(short)f2bf(q.y); o[2]=(short)f2bf(q.z); o[3]=(short)f2bf(q.w);
      *(s16x4*)(dst + e0) = o;
      return;
    }
  }
}

// ---------------- token-shift mix -> 6 bf16 arrays (once) ----------------
__global__ __launch_bounds__(256) void prep_k(
    const float* __restrict__ x,
    const float* __restrict__ cr, const float* __restrict__ cw, const float* __restrict__ ck,
    const float* __restrict__ cv, const float* __restrict__ ca, const float* __restrict__ cg,
    unsigned short* __restrict__ xr, unsigned short* __restrict__ xw, unsigned short* __restrict__ xk,
    unsigned short* __restrict__ xv, unsigned short* __restrict__ xa, unsigned short* __restrict__ xg)
{
  const int m = blockIdx.x;
  const int c = threadIdx.x * 4;
  const size_t ix = (size_t)m * 1024 + c;
  const f32x4 q = *(const f32x4*)(x + ix);
  f32x4 s = {0.f,0.f,0.f,0.f};
  if ((m & (TSEQ - 1)) != 0) s = *(const f32x4*)(x + ix - 1024);
  const f32x4 d = s - q;
  #define DO_MIX(coef, out) { \
    const f32x4 mc = *(const f32x4*)(coef + c); \
    s16x4 o; \
    o[0]=(short)f2bf(fmaf(d.x, mc.x, q.x)); o[1]=(short)f2bf(fmaf(d.y, mc.y, q.y)); \
    o[2]=(short)f2bf(fmaf(d.z, mc.z, q.z)); o[3]=(short)f2bf(fmaf(d.w, mc.w, q.w)); \
    *(s16x4*)(out + ix) = o; }
  DO_MIX(cr, xr); DO_MIX(cw, xw); DO_MIX(ck, xk);
  DO_MIX(cv, xv); DO_MIX(ca, xa); DO_MIX(cg, xg);
  #undef DO_MIX
}

// ---------------- bf16 MFMA GEMM, 64x128 tile, g2l double buffer, 2 blocks/CU ----
#define EPI_F32 0
#define EPI_BF16 1
#define EPI_TANH_BF16 2
#define EPI_SIG_BF16 3
#define EPI_PK_F32 4
#define EPI_PK_SIG 5
#define EPI_PK_DECAY 6

template<int EPI, int ARR>
__global__ __launch_bounds__(256) void gemm_k(
    const unsigned short* __restrict__ ABF,    // (M,K) bf16
    const unsigned short* __restrict__ BBF,    // (N,K) bf16 (rows beyond N readable)
    void* __restrict__ Cout,
    const float* __restrict__ bias, const float* __restrict__ w0,
    int M, int N, int K)
{
  __shared__ unsigned short As[2][64][32];     // 4KB per buf
  __shared__ unsigned short Bs[2][128][32];    // 8KB per buf
  const int tid  = threadIdx.x;
  const int m0   = blockIdx.y * 64;
  const int n0   = blockIdx.x * 128;
  const int srow = tid >> 2;                   // 0..63
  const int scol = (tid & 3) << 3;             // 0,8,16,24
  const int wofs = (tid >> 6) << 10;           // wave*1024 bytes
  const int lane = tid & 63;
  const int wv   = tid >> 6;
  const int wr   = (wv >> 1) << 5;             // 0 or 32
  const int wc   = (wv & 1) << 6;              // 0 or 64
  const int lr   = lane & 15;
  const int lg   = lane >> 4;

#define STAGE(BUF, KOFF) { \
    const unsigned short* a0 = ABF + (size_t)(m0 + srow) * K + (KOFF) + scol; \
    const unsigned short* b0 = BBF + (size_t)(n0 + srow) * K + (KOFF) + scol; \
    g2l16(a0,                 (char*)&As[BUF][0][0] + wofs); \
    g2l16(b0,                 (char*)&Bs[BUF][0][0] + wofs); \
    g2l16(b0 + (size_t)64*K,  (char*)&Bs[BUF][0][0] + 4096 + wofs); }

  f32x4 acc[2][4];
  #pragma unroll
  for (int i = 0; i < 2; i++)
    #pragma unroll
    for (int j = 0; j < 4; j++) acc[i][j] = f32x4{0.f, 0.f, 0.f, 0.f};

  STAGE(0, 0)
  __syncthreads();

  int buf = 0;
  for (int k0 = 0; k0 < K; k0 += 32){
    if (k0 + 32 < K){ STAGE(buf ^ 1, k0 + 32) }
    s16x8 af[2], bfr[4];
    #pragma unroll
    for (int i = 0; i < 2; i++) af[i]  = *(const s16x8*)&As[buf][wr + i*16 + lr][lg*8];
    #pragma unroll
    for (int j = 0; j < 4; j++) bfr[j] = *(const s16x8*)&Bs[buf][wc + j*16 + lr][lg*8];
    #pragma unroll
    for (int i = 0; i < 2; i++)
      #pragma unroll
      for (int j = 0; j < 4; j++)
        acc[i][j] = __builtin_amdgcn_mfma_f32_16x16x32_bf16(af[i], bfr[j], acc[i][j], 0, 0, 0);
    __syncthreads();
    buf ^= 1;
  }
#undef STAGE

  #pragma unroll
  for (int i = 0; i < 2; i++){
    const int mb = m0 + wr + i*16 + lg*4;
    #pragma unroll
    for (int j = 0; j < 4; j++){
      const int n = n0 + wc + j*16 + lr;
      if (n < N){
        #pragma unroll
        for (int q = 0; q < 4; q++){
          const int m = mb + q;
          const float val = acc[i][j][q];
          if constexpr (EPI == EPI_PK_F32 || EPI == EPI_PK_SIG || EPI == EPI_PK_DECAY){
            const int b2 = m >> 11, t2 = m & 2047, h2 = n >> 6, ch = n & 63;
            const size_t pix = (size_t)(b2*16 + h2) * (TSEQ*384) + (size_t)t2*384 + ARR*64 + ch;
            if constexpr (EPI == EPI_PK_F32) ((float*)Cout)[pix] = val;
            else if constexpr (EPI == EPI_PK_SIG) ((float*)Cout)[pix] = sigf(val + bias[n]);
            else {
              float z = val + bias[n] + w0[n];
              ((float*)Cout)[pix] = expf(-0.60653065971263342f * sigf(z));
            }
          } else {
            const size_t oix = (size_t)m * N + n;
            if constexpr (EPI == EPI_F32)            ((float*)Cout)[oix] = val;
            else if constexpr (EPI == EPI_BF16)      ((unsigned short*)Cout)[oix] = f2bf(val);
            else if constexpr (EPI == EPI_TANH_BF16) ((unsigned short*)Cout)[oix] = f2bf(tanhf(val));
            else if constexpr (EPI == EPI_SIG_BF16)  ((unsigned short*)Cout)[oix] = f2bf(sigf(val));
          }
        }
      }
    }
  }
}

// ---------------- kk normalize (in pk): k_raw,a_raw -> k_scaled, b, -kk ----------------
__global__ __launch_bounds__(256) void kkprep2_k(
    float* __restrict__ pk, const float* __restrict__ kkc, const float* __restrict__ kac)
{
  const int flat = blockIdx.x * 4 + (threadIdx.x >> 6);   // (bh, t)
  const int lane = threadIdx.x & 63;
  const int bh = flat >> 11, t = flat & 2047;
  const size_t pb = (size_t)bh * (TSEQ*384) + (size_t)t * 384;
  const int c = (bh & 15) * 64 + lane;
  const float kraw = pk[pb + 128 + lane];
  const float araw = pk[pb + 192 + lane];
  const float tt = kraw * kkc[c];
  const float ss = wredsum(tt * tt);
  const float kkv = tt / fmaxf(sqrtf(ss), 1e-12f);
  pk[pb + 128 + lane] = kraw * (1.f + (araw - 1.f) * kac[c]);
  pk[pb + 192 + lane] = kkv * araw;     // b_in
  pk[pb + 256 + lane] = -kkv;           // a_in (pre-negated)
}

// ---------------- RWKV-7 scan (ROUND-12 PROVEN): ring-32, double-buffered sets ----
__global__ __launch_bounds__(64) void scan_k(
    const float* __restrict__ pk, float* __restrict__ o)
{
  const int lane = threadIdx.x;
  const int L = lane & 15, g = lane >> 4;
  const int f = blockIdx.x;
  const int grp = (f >> 3) & 15;
  const int bh  = ((f >> 7) << 3) | (f & 7);
  const int b_  = bh >> 4, h_ = bh & 15;
  const size_t pkb = (size_t)bh * (TSEQ * 384);
  const int vq = 4 * L;
  const int vrow = grp * 4 + g;

  __shared__ float lds[8][1536];    // 48 KB
  int mload = 0;                    // next group to load

#define G2LG(SLOT) { \
    const int mc = (mload < TSEQ/4) ? mload : (TSEQ/4 - 1); \
    const float* src = pk + pkb + (size_t)mc * 1536 + lane * 4; \
    g2l16f(src +    0, &lds[SLOT][0]);    \
    g2l16f(src +  256, &lds[SLOT][256]);  \
    g2l16f(src +  512, &lds[SLOT][512]);  \
    g2l16f(src +  768, &lds[SLOT][768]);  \
    g2l16f(src + 1024, &lds[SLOT][1024]); \
    g2l16f(src + 1280, &lds[SLOT][1280]); \
    mload++; }

  f32x4 Rg[8], Wg[8], Kg[8], Bg[8], Ag[8]; float Vg[8];

#define PREF1(SLOT, I, SET) { \
    const float* pb_ = &lds[SLOT][(I)*384]; \
    Rg[SET] = *(const f32x4*)(pb_ + vq); \
    Wg[SET] = *(const f32x4*)(pb_ + 64 + vq); \
    Kg[SET] = *(const f32x4*)(pb_ + 128 + vq); \
    Bg[SET] = *(const f32x4*)(pb_ + 192 + vq); \
    Ag[SET] = *(const f32x4*)(pb_ + 256 + vq); \
    Vg[SET] = pb_[320 + vrow]; }
#define PREF4(SLOT, SB) PREF1(SLOT,0,SB+0) PREF1(SLOT,1,SB+1) PREF1(SLOT,2,SB+2) PREF1(SLOT,3,SB+3)

  f32x4 S = {0.f, 0.f, 0.f, 0.f};
  float oreg = 0.f;

#define STEP(I, SIDX) { \
    const float p = fmaf(S.y, Ag[I].y, S.x * Ag[I].x) + fmaf(S.w, Ag[I].w, S.z * Ag[I].z); \
    const float sa = red16(p); \
    const float cv = Vg[I]; \
    S.x = fmaf(S.x, Wg[I].x, fmaf(sa, Bg[I].x, cv * Kg[I].x)); \
    S.y = fmaf(S.y, Wg[I].y, fmaf(sa, Bg[I].y, cv * Kg[I].y)); \
    S.z = fmaf(S.z, Wg[I].z, fmaf(sa, Bg[I].z, cv * Kg[I].z)); \
    S.w = fmaf(S.w, Wg[I].w, fmaf(sa, Bg[I].w, cv * Kg[I].w)); \
    const float q = fmaf(S.y, Rg[I].y, S.x * Rg[I].x) + fmaf(S.w, Rg[I].w, S.z * Rg[I].z); \
    const float oo = red16(q); \
    oreg = (L == (SIDX)) ? oo : oreg; }

#define VMW(N) asm volatile("s_waitcnt vmcnt(" #N ")" ::: "memory");

  // Per seq J: wait group landed -> PREF next slot -> STEP current sets -> refill.
#define SEQ(J, PSET, CSET) \
    VMW(36) \
    PREF4((J+1)&7, PSET) \
    STEP(CSET+0, ((J)&3)*4+0) STEP(CSET+1, ((J)&3)*4+1) \
    STEP(CSET+2, ((J)&3)*4+2) STEP(CSET+3, ((J)&3)*4+3) \
    G2LG(J)

  // prologue: groups 0..7, prime sets A with group 0
  G2LG(0) G2LG(1) G2LG(2) G2LG(3) G2LG(4) G2LG(5) G2LG(6) G2LG(7)
  VMW(42)
  PREF4(0, 0)

  const size_t ob = (size_t)b_ * (TSEQ*1024) + h_*64;
  for (int ot = 0; ot < TSEQ/32; ++ot){
    SEQ(0,4,0) SEQ(1,0,4) SEQ(2,4,0) SEQ(3,0,4)
    o[ob + (size_t)(32*ot + L) * 1024 + vrow] = oreg;        // steps 32ot..+15
    SEQ(4,4,0) SEQ(5,0,4) SEQ(6,4,0) SEQ(7,0,4)
    o[ob + (size_t)(32*ot + 16 + L) * 1024 + vrow] = oreg;   // steps 32ot+16..+31
  }

#undef G2LG
#undef PREF1
#undef PREF4
#undef STEP
#undef VMW
#undef SEQ
}

// ---------------- GroupNorm + bonus + gate -> y (bf16) ----------------
__global__ __launch_bounds__(256) void gnout_k(
    const float* __restrict__ pk, const float* __restrict__ o, const float* __restrict__ g_,
    const float* __restrict__ rk, const float* __restrict__ gnw, const float* __restrict__ gnb,
    unsigned short* __restrict__ y)
{
  const int flat = blockIdx.x * 4 + (threadIdx.x >> 6);  // (bh, t)
  const int lane = threadIdx.x & 63;
  const int bh = flat >> 11, t = flat & 2047;
  const int b_ = bh >> 4, h_ = bh & 15;
  const size_t pb = (size_t)bh * (TSEQ*384) + (size_t)t * 384;
  const int c = h_*64 + lane;
  const size_t fi = (size_t)(b_*2048 + t) * 1024 + c;
  const float rv = pk[pb + lane];
  const float kv = pk[pb + 128 + lane];
  const float vv = pk[pb + 320 + lane];
  const float ov = o[fi];
  const float mu  = wredsum(ov) * 0.015625f;
  const float d   = ov - mu;
  const float var = wredsum(d * d) * 0.015625f;
  const float on  = d * rsqrtf(var + 6.4e-4f) * gnw[c] + gnb[c];   // eps = D*1e-5
  const float s   = wredsum(rv * kv * rk[c]);
  const float yv  = (on + s * vv) * g_[fi];
  y[fi] = f2bf(yv);
}

extern "C" void kernel_launch(void* const* d_in, const int* in_sizes, int n_in,
                              void* d_out, int out_size, void* d_ws, size_t ws_size,
                              hipStream_t stream)
{
  const float* x    = (const float*)d_in[0];
  const float* x_r  = (const float*)d_in[1];
  const float* x_w  = (const float*)d_in[2];
  const float* x_k  = (const float*)d_in[3];
  const float* x_v  = (const float*)d_in[4];
  const float* x_a  = (const float*)d_in[5];
  const float* x_g  = (const float*)d_in[6];
  const float* k_k  = (const float*)d_in[7];
  const float* k_a  = (const float*)d_in[8];
  const float* r_k  = (const float*)d_in[9];
  const float* Wr   = (const float*)d_in[10];
  const float* Wk   = (const float*)d_in[11];
  const float* Wv   = (const float*)d_in[12];
  const float* Wo   = (const float*)d_in[13];
  const float* wA   = (const float*)d_in[14];
  const float* wB   = (const float*)d_in[15];
  const float* wbias= (const float*)d_in[16];
  const float* aA   = (const float*)d_in[17];
  const float* aB   = (const float*)d_in[18];
  const float* abias= (const float*)d_in[19];
  const float* gA   = (const float*)d_in[20];
  const float* gB   = (const float*)d_in[21];
  const float* gnw  = (const float*)d_in[22];
  const float* gnb  = (const float*)d_in[23];
  const float* w0b  = (const float*)d_in[24];
  const float* w0d  = (const float*)d_in[25];

  char* ws = (char*)d_ws;
  const size_t MB = 1024ull * 1024ull;
  const size_t KB = 1024ull;

  // Memory plan (max 149 MB):
  float*          pk_  = (float*)(ws + 0);                 // 0..96MB packed [r|w|k|b|-kk|v]
  unsigned short* xw_  = (unsigned short*)(ws + 0*MB);     // in pk, dead before pk writes
  unsigned short* xa_  = (unsigned short*)(ws + 8*MB);     // in pk
  unsigned short* xg_  = (unsigned short*)(ws + 16*MB);    // in pk
  float*          g_   = (float*)(ws + 96*MB);             // 96..112
  unsigned short* xr_  = (unsigned short*)(ws + 96*MB);    // in g_, dead before g_ write
  unsigned short* xk_  = (unsigned short*)(ws + 104*MB);   // in g_
  unsigned short* y_   = (unsigned short*)(ws + 112*MB);   // 112..120
  unsigned short* xv_  = (unsigned short*)(ws + 112*MB);   // in y_, dead before y write
  unsigned short* wbf_ = (unsigned short*)(ws + 120*MB);   // 120..130 (9.6MB)
  unsigned short* wl1_ = (unsigned short*)(ws + 130*MB);
  unsigned short* al1_ = (unsigned short*)(ws + 130*MB + 512*KB);
  unsigned short* gl1_ = (unsigned short*)(ws + 131*MB);   // 1.25MB
  float*          w0_  = (float*)(ws + 132*MB + 512*KB);
  float*          o_   = (float*)(ws + 133*MB);            // 133..149

  const unsigned short* bWr = wbf_ + 0;
  const unsigned short* bWk = wbf_ + 1048576;
  const unsigned short* bWv = wbf_ + 2097152;
  const unsigned short* bWo = wbf_ + 3145728;
  const unsigned short* bwA = wbf_ + 4194304;
  const unsigned short* bwB = wbf_ + 4259840;
  const unsigned short* baA = wbf_ + 4325376;
  const unsigned short* baB = wbf_ + 4390912;
  const unsigned short* bgA = wbf_ + 4456448;
  const unsigned short* bgB = wbf_ + 4620288;

  const dim3 blk(256);
  const dim3 gBig(8, 64), gN64(1, 64), gN160(2, 64);

  w0_scan_k<<<dim3(1), dim3(1024), 0, stream>>>(w0b, w0d, w0_);

  WCvtArgs wargs;
  wargs.src[0]=Wr; wargs.src[1]=Wk; wargs.src[2]=Wv; wargs.src[3]=Wo;
  wargs.src[4]=wA; wargs.src[5]=wB; wargs.src[6]=aA; wargs.src[7]=aB;
  wargs.src[8]=gA; wargs.src[9]=gB;
  wcvt_k<<<dim3(WTOT/4/256), blk, 0, stream>>>(wargs, wbf_);

  prep_k<<<dim3(4096), blk, 0, stream>>>(x, x_r, x_w, x_k, x_v, x_a, x_g,
                                         xr_, xw_, xk_, xv_, xa_, xg_);

  // LoRA stage-1 first (xw/xa/xg die before pk is written)
  gemm_k<EPI_TANH_BF16,0><<<gN64, blk, 0, stream>>>(xw_, bwA, wl1_, nullptr, nullptr, 4096, 64, 1024);
  gemm_k<EPI_BF16,0><<<gN64, blk, 0, stream>>>(xa_, baA, al1_, nullptr, nullptr, 4096, 64, 1024);
  gemm_k<EPI_SIG_BF16,0><<<gN160, blk, 0, stream>>>(xg_, bgA, gl1_, nullptr, nullptr, 4096, 160, 1024);

  // projections -> pk slots
  gemm_k<EPI_PK_F32,0><<<gBig, blk, 0, stream>>>(xr_, bWr, pk_, nullptr, nullptr, 4096, 1024, 1024);
  gemm_k<EPI_PK_F32,2><<<gBig, blk, 0, stream>>>(xk_, bWk, pk_, nullptr, nullptr, 4096, 1024, 1024);
  gemm_k<EPI_PK_F32,5><<<gBig, blk, 0, stream>>>(xv_, bWv, pk_, nullptr, nullptr, 4096, 1024, 1024);

  // LoRA stage-2 -> pk slots (decay into arr1, a into arr3)
  gemm_k<EPI_PK_DECAY,1><<<gBig, blk, 0, stream>>>(wl1_, bwB, pk_, wbias, w0_, 4096, 1024, 64);
  gemm_k<EPI_PK_SIG,3><<<gBig, blk, 0, stream>>>(al1_, baB, pk_, abias, nullptr, 4096, 1024, 64);

  // gate -> flat g_
  gemm_k<EPI_F32,0><<<gBig, blk, 0, stream>>>(gl1_, bgB, g_, nullptr, nullptr, 4096, 1024, 160);

  // k/b/kk finalize inside pk
  kkprep2_k<<<dim3(16384), blk, 0, stream>>>(pk_, k_k, k_a);

  // sequential recurrence (round-12 proven scan)
  scan_k<<<dim3(512), dim3(64), 0, stream>>>(pk_, o_);

  // GroupNorm + bonus + gate
  gnout_k<<<dim3(16384), blk, 0, stream>>>(pk_, o_, g_, r_k, gnw, gnb, y_);

  // output projection
  gemm_k<EPI_F32,0><<<gBig, blk, 0, stream>>>(y_, bWo, (float*)d_out, nullptr, nullptr, 4096, 1024, 1024);
}

// Round 15
// 448.635 us; speedup vs baseline: 1.2895x; 1.0024x over previous
//
#include <hip/hip_runtime.h>
#include <hip/hip_bf16.h>
#include <math.h>

typedef float f32x4 __attribute__((ext_vector_type(4)));
typedef short s16x8 __attribute__((ext_vector_type(8)));
typedef short s16x4 __attribute__((ext_vector_type(4)));

#define TSEQ 2048

__device__ __forceinline__ unsigned short f2bf(float f){
  unsigned int u = __builtin_bit_cast(unsigned int, f);
  u += 0x7FFFu + ((u >> 16) & 1u);
  return (unsigned short)(u >> 16);
}
__device__ __forceinline__ float sigf(float x){ return 1.0f / (1.0f + __expf(-x)); }
__device__ __forceinline__ float wredsum(float x){
  #pragma unroll
  for (int off = 32; off > 0; off >>= 1) x += __shfl_xor(x, off);
  return x;
}

// 16-lane-group sum via DPP — no LDS.
template<int CTRL>
__device__ __forceinline__ float dpp_add(float x){
  int v = __builtin_amdgcn_update_dpp(0, __builtin_bit_cast(int, x), CTRL, 0xF, 0xF, true);
  return x + __builtin_bit_cast(float, v);
}
__device__ __forceinline__ float red16(float x){
  x = dpp_add<0xB1>(x);   // quad_perm [1,0,3,2]
  x = dpp_add<0x4E>(x);   // quad_perm [2,3,0,1]
  x = dpp_add<0x124>(x);  // row_ror:4
  x = dpp_add<0x128>(x);  // row_ror:8
  return x;
}

// async global->LDS, 16B per lane: dest = uniform base + lane*16, src per-lane.
__device__ __forceinline__ void g2l16(const unsigned short* gp, void* lp){
  __builtin_amdgcn_global_load_lds(
    (const __attribute__((address_space(1))) unsigned int*)gp,
    (__attribute__((address_space(3))) unsigned int*)lp, 16, 0, 0);
}
__device__ __forceinline__ void g2l16f(const float* gp, void* lp){
  __builtin_amdgcn_global_load_lds(
    (const __attribute__((address_space(1))) unsigned int*)gp,
    (__attribute__((address_space(3))) unsigned int*)lp, 16, 0, 0);
}

// ---------------- w0 prefix-scan (C=1024) ----------------
__global__ void w0_scan_k(const float* __restrict__ w0b, const float* __restrict__ w0d,
                          float* __restrict__ w0){
  __shared__ float buf[1024];
  int i = threadIdx.x;
  float v = 0.f;
  if (i > 0){
    float d = w0d[i-1];
    v = (d > 20.f) ? d : log1pf(__expf(d));   // softplus
  }
  buf[i] = v;
  __syncthreads();
  for (int off = 1; off < 1024; off <<= 1){
    float t = (i >= off) ? buf[i - off] : 0.f;
    __syncthreads();
    buf[i] += t;
    __syncthreads();
  }
  w0[i] = w0b[0] + buf[i];
}

// ---------------- convert all weights f32 -> bf16 (once) ----------------
struct WCvtArgs { const float* src[10]; };
__constant__ const int WCSUM[11] = {0, 1048576, 2097152, 3145728, 4194304,
                                    4259840, 4325376, 4390912, 4456448, 4620288, 4784128};
#define WTOT 4784128

__global__ __launch_bounds__(256) void wcvt_k(WCvtArgs args, unsigned short* __restrict__ dst){
  const int e0 = (blockIdx.x * 256 + threadIdx.x) * 4;
  #pragma unroll
  for (int i = 0; i < 10; i++){
    if (e0 < WCSUM[i+1]){
      const f32x4 q = *(const f32x4*)(args.src[i] + (e0 - WCSUM[i]));
      s16x4 o; o[0]=(short)f2bf(q.x); o[1]=(short)f2bf(q.y); o[2]=(short)f2bf(q.z); o[3]=(short)f2bf(q.w);
      *(s16x4*)(dst + e0) = o;
      return;
    }
  }
}

// ---------------- token-shift mix -> 6 bf16 arrays (once) ----------------
__global__ __launch_bounds__(256) void prep_k(
    const float* __restrict__ x,
    const float* __restrict__ cr, const float* __restrict__ cw, const float* __restrict__ ck,
    const float* __restrict__ cv, const float* __restrict__ ca, const float* __restrict__ cg,
    unsigned short* __restrict__ xr, unsigned short* __restrict__ xw, unsigned short* __restrict__ xk,
    unsigned short* __restrict__ xv, unsigned short* __restrict__ xa, unsigned short* __restrict__ xg)
{
  const int m = blockIdx.x;
  const int c = threadIdx.x * 4;
  const size_t ix = (size_t)m * 1024 + c;
  const f32x4 q = *(const f32x4*)(x + ix);
  f32x4 s = {0.f,0.f,0.f,0.f};
  if ((m & (TSEQ - 1)) != 0) s = *(const f32x4*)(x + ix - 1024);
  const f32x4 d = s - q;
  #define DO_MIX(coef, out) { \
    const f32x4 mc = *(const f32x4*)(coef + c); \
    s16x4 o; \
    o[0]=(short)f2bf(fmaf(d.x, mc.x, q.x)); o[1]=(short)f2bf(fmaf(d.y, mc.y, q.y)); \
    o[2]=(short)f2bf(fmaf(d.z, mc.z, q.z)); o[3]=(short)f2bf(fmaf(d.w, mc.w, q.w)); \
    *(s16x4*)(out + ix) = o; }
  DO_MIX(cr, xr); DO_MIX(cw, xw); DO_MIX(ck, xk);
  DO_MIX(cv, xv); DO_MIX(ca, xa); DO_MIX(cg, xg);
  #undef DO_MIX
}

// ---------------- bf16 MFMA GEMM, 64x128 tile, g2l double buffer, 2 blocks/CU ----
#define EPI_F32 0
#define EPI_BF16 1
#define EPI_TANH_BF16 2
#define EPI_SIG_BF16 3
#define EPI_PK_F32 4
#define EPI_PK_SIG 5
#define EPI_PK_DECAY 6

template<int EPI, int ARR>
__global__ __launch_bounds__(256) void gemm_k(
    const unsigned short* __restrict__ ABF,    // (M,K) bf16
    const unsigned short* __restrict__ BBF,    // (N,K) bf16 (rows beyond N readable)
    void* __restrict__ Cout,
    const float* __restrict__ bias, const float* __restrict__ w0,
    int M, int N, int K)
{
  __shared__ unsigned short As[2][64][32];     // 4KB per buf
  __shared__ unsigned short Bs[2][128][32];    // 8KB per buf
  const int tid  = threadIdx.x;
  const int m0   = blockIdx.y * 64;
  const int n0   = blockIdx.x * 128;
  const int srow = tid >> 2;                   // 0..63
  const int scol = (tid & 3) << 3;             // 0,8,16,24
  const int wofs = (tid >> 6) << 10;           // wave*1024 bytes
  const int lane = tid & 63;
  const int wv   = tid >> 6;
  const int wr   = (wv >> 1) << 5;             // 0 or 32
  const int wc   = (wv & 1) << 6;              // 0 or 64
  const int lr   = lane & 15;
  const int lg   = lane >> 4;

#define STAGE(BUF, KOFF) { \
    const unsigned short* a0 = ABF + (size_t)(m0 + srow) * K + (KOFF) + scol; \
    const unsigned short* b0 = BBF + (size_t)(n0 + srow) * K + (KOFF) + scol; \
    g2l16(a0,                 (char*)&As[BUF][0][0] + wofs); \
    g2l16(b0,                 (char*)&Bs[BUF][0][0] + wofs); \
    g2l16(b0 + (size_t)64*K,  (char*)&Bs[BUF][0][0] + 4096 + wofs); }

  f32x4 acc[2][4];
  #pragma unroll
  for (int i = 0; i < 2; i++)
    #pragma unroll
    for (int j = 0; j < 4; j++) acc[i][j] = f32x4{0.f, 0.f, 0.f, 0.f};

  STAGE(0, 0)
  __syncthreads();

  int buf = 0;
  for (int k0 = 0; k0 < K; k0 += 32){
    if (k0 + 32 < K){ STAGE(buf ^ 1, k0 + 32) }
    s16x8 af[2], bfr[4];
    #pragma unroll
    for (int i = 0; i < 2; i++) af[i]  = *(const s16x8*)&As[buf][wr + i*16 + lr][lg*8];
    #pragma unroll
    for (int j = 0; j < 4; j++) bfr[j] = *(const s16x8*)&Bs[buf][wc + j*16 + lr][lg*8];
    #pragma unroll
    for (int i = 0; i < 2; i++)
      #pragma unroll
      for (int j = 0; j < 4; j++)
        acc[i][j] = __builtin_amdgcn_mfma_f32_16x16x32_bf16(af[i], bfr[j], acc[i][j], 0, 0, 0);
    __syncthreads();
    buf ^= 1;
  }
#undef STAGE

  #pragma unroll
  for (int i = 0; i < 2; i++){
    const int mb = m0 + wr + i*16 + lg*4;
    #pragma unroll
    for (int j = 0; j < 4; j++){
      const int n = n0 + wc + j*16 + lr;
      if (n < N){
        #pragma unroll
        for (int q = 0; q < 4; q++){
          const int m = mb + q;
          const float val = acc[i][j][q];
          if constexpr (EPI == EPI_PK_F32 || EPI == EPI_PK_SIG || EPI == EPI_PK_DECAY){
            const int b2 = m >> 11, t2 = m & 2047, h2 = n >> 6, ch = n & 63;
            const size_t pix = (size_t)(b2*16 + h2) * (TSEQ*384) + (size_t)t2*384 + ARR*64 + ch;
            if constexpr (EPI == EPI_PK_F32) ((float*)Cout)[pix] = val;
            else if constexpr (EPI == EPI_PK_SIG) ((float*)Cout)[pix] = sigf(val + bias[n]);
            else {
              float z = val + bias[n] + w0[n];
              ((float*)Cout)[pix] = expf(-0.60653065971263342f * sigf(z));
            }
          } else {
            const size_t oix = (size_t)m * N + n;
            if constexpr (EPI == EPI_F32)            ((float*)Cout)[oix] = val;
            else if constexpr (EPI == EPI_BF16)      ((unsigned short*)Cout)[oix] = f2bf(val);
            else if constexpr (EPI == EPI_TANH_BF16) ((unsigned short*)Cout)[oix] = f2bf(tanhf(val));
            else if constexpr (EPI == EPI_SIG_BF16)  ((unsigned short*)Cout)[oix] = f2bf(sigf(val));
          }
        }
      }
    }
  }
}

// ---------------- kk normalize (in pk): k_raw,a_raw -> k_scaled, b, -kk ----------------
__global__ __launch_bounds__(256) void kkprep2_k(
    float* __restrict__ pk, const float* __restrict__ kkc, const float* __restrict__ kac)
{
  const int flat = blockIdx.x * 4 + (threadIdx.x >> 6);   // (bh, t)
  const int lane = threadIdx.x & 63;
  const int bh = flat >> 11, t = flat & 2047;
  const size_t pb = (size_t)bh * (TSEQ*384) + (size_t)t * 384;
  const int c = (bh & 15) * 64 + lane;
  const float kraw = pk[pb + 128 + lane];
  const float araw = pk[pb + 192 + lane];
  const float tt = kraw * kkc[c];
  const float ss = wredsum(tt * tt);
  const float kkv = tt / fmaxf(sqrtf(ss), 1e-12f);
  pk[pb + 128 + lane] = kraw * (1.f + (araw - 1.f) * kac[c]);
  pk[pb + 192 + lane] = kkv * araw;     // b_in
  pk[pb + 256 + lane] = -kkv;           // a_in (pre-negated)
}

// ---------------- RWKV-7 scan: ring-32, 2-step double-buffered register pairs ------
// r12 invariants preserved: (1) PREF targets a slot AHEAD of the refill pointer,
// (2) refill of slot J is one asm-barrier-separated region after slot J's last
// ds_read, (3) VMW(36) algebra identical (completed >= 12+6J+stores => group J+1).
// Change vs r12: register sets = 4 x (2-step pair) instead of 8 x (4-step) —
// ~110 VGPR fits the 128 tier, so the allocator keeps the full double buffer
// resident (r12's 132<168 caused PREF sinking -> ~200 cyc/step lgkm stalls).
__global__ __launch_bounds__(64) void scan_k(
    const float* __restrict__ pk, float* __restrict__ o)
{
  const int lane = threadIdx.x;
  const int L = lane & 15, g = lane >> 4;
  const int f = blockIdx.x;
  const int grp = (f >> 3) & 15;
  const int bh  = ((f >> 7) << 3) | (f & 7);
  const int b_  = bh >> 4, h_ = bh & 15;
  const size_t pkb = (size_t)bh * (TSEQ * 384);
  const int vq = 4 * L;
  const int vrow = grp * 4 + g;

  __shared__ float lds[8][1536];    // 48 KB ring: 8 groups x 4 steps
  int mload = 0;                    // next group to load

#define G2LG(SLOT) { \
    const int mc = (mload < TSEQ/4) ? mload : (TSEQ/4 - 1); \
    const float* src = pk + pkb + (size_t)mc * 1536 + lane * 4; \
    g2l16f(src +    0, &lds[SLOT][0]);    \
    g2l16f(src +  256, &lds[SLOT][256]);  \
    g2l16f(src +  512, &lds[SLOT][512]);  \
    g2l16f(src +  768, &lds[SLOT][768]);  \
    g2l16f(src + 1024, &lds[SLOT][1024]); \
    g2l16f(src + 1280, &lds[SLOT][1280]); \
    mload++; }

  f32x4 Rg[4], Wg[4], Kg[4], Bg[4], Ag[4]; float Vg[4];

#define PREF1(SLOT, I, SET) { \
    const float* pb_ = &lds[SLOT][(I)*384]; \
    Rg[SET] = *(const f32x4*)(pb_ + vq); \
    Wg[SET] = *(const f32x4*)(pb_ + 64 + vq); \
    Kg[SET] = *(const f32x4*)(pb_ + 128 + vq); \
    Bg[SET] = *(const f32x4*)(pb_ + 192 + vq); \
    Ag[SET] = *(const f32x4*)(pb_ + 256 + vq); \
    Vg[SET] = pb_[320 + vrow]; }
#define PREF2(SLOT, HALF, S0, S1) PREF1(SLOT,(HALF)*2,S0) PREF1(SLOT,(HALF)*2+1,S1)

  f32x4 S = {0.f, 0.f, 0.f, 0.f};
  float oreg = 0.f;

#define STEP(I, SIDX) { \
    const float p = fmaf(S.y, Ag[I].y, S.x * Ag[I].x) + fmaf(S.w, Ag[I].w, S.z * Ag[I].z); \
    const float sa = red16(p); \
    const float cv = Vg[I]; \
    S.x = fmaf(S.x, Wg[I].x, fmaf(sa, Bg[I].x, cv * Kg[I].x)); \
    S.y = fmaf(S.y, Wg[I].y, fmaf(sa, Bg[I].y, cv * Kg[I].y)); \
    S.z = fmaf(S.z, Wg[I].z, fmaf(sa, Bg[I].z, cv * Kg[I].z)); \
    S.w = fmaf(S.w, Wg[I].w, fmaf(sa, Bg[I].w, cv * Kg[I].w)); \
    const float q = fmaf(S.y, Rg[I].y, S.x * Rg[I].x) + fmaf(S.w, Rg[I].w, S.z * Rg[I].z); \
    const float oo = red16(q); \
    oreg = (L == (SIDX)) ? oo : oreg; }

#define VMW(N) asm volatile("s_waitcnt vmcnt(" #N ")" ::: "memory");

  // Ha(J): consume pair0 = (slot J, steps 0-1); prefetch pair1 = (slot J, steps 2-3).
  // Hb(J): VMW(36) [group J+1 landed]; prefetch pair0 = (slot J+1, steps 0-1);
  //        consume pair1; refill slot J (last read of slot J was in Ha, across VMW).
#define HSEQA(J, SX) \
    PREF2(J, 1, 2, 3) \
    STEP(0, (SX)+0) STEP(1, (SX)+1)

#define HSEQB(J, SX) \
    VMW(36) \
    PREF2(((J)+1)&7, 0, 0, 1) \
    STEP(2, (SX)+2) STEP(3, (SX)+3) \
    G2LG(J)

  // prologue: fill ring with groups 0..7; prime pair0 with (slot 0, steps 0-1)
  G2LG(0) G2LG(1) G2LG(2) G2LG(3) G2LG(4) G2LG(5) G2LG(6) G2LG(7)
  VMW(42)
  PREF2(0, 0, 0, 1)

  const size_t ob = (size_t)b_ * (TSEQ*1024) + h_*64;
  for (int ot = 0; ot < TSEQ/32; ++ot){
    HSEQA(0,0)  HSEQB(0,0)
    HSEQA(1,4)  HSEQB(1,4)
    HSEQA(2,8)  HSEQB(2,8)
    HSEQA(3,12) HSEQB(3,12)
    o[ob + (size_t)(32*ot + L) * 1024 + vrow] = oreg;        // steps 32ot..+15
    HSEQA(4,0)  HSEQB(4,0)
    HSEQA(5,4)  HSEQB(5,4)
    HSEQA(6,8)  HSEQB(6,8)
    HSEQA(7,12) HSEQB(7,12)
    o[ob + (size_t)(32*ot + 16 + L) * 1024 + vrow] = oreg;   // steps 32ot+16..+31
  }

#undef G2LG
#undef PREF1
#undef PREF2
#undef STEP
#undef VMW
#undef HSEQA
#undef HSEQB
}

// ---------------- GroupNorm + bonus + gate -> y (bf16) ----------------
__global__ __launch_bounds__(256) void gnout_k(
    const float* __restrict__ pk, const float* __restrict__ o, const float* __restrict__ g_,
    const float* __restrict__ rk, const float* __restrict__ gnw, const float* __restrict__ gnb,
    unsigned short* __restrict__ y)
{
  const int flat = blockIdx.x * 4 + (threadIdx.x >> 6);  // (bh, t)
  const int lane = threadIdx.x & 63;
  const int bh = flat >> 11, t = flat & 2047;
  const int b_ = bh >> 4, h_ = bh & 15;
  const size_t pb = (size_t)bh * (TSEQ*384) + (size_t)t * 384;
  const int c = h_*64 + lane;
  const size_t fi = (size_t)(b_*2048 + t) * 1024 + c;
  const float rv = pk[pb + lane];
  const float kv = pk[pb + 128 + lane];
  const float vv = pk[pb + 320 + lane];
  const float ov = o[fi];
  const float mu  = wredsum(ov) * 0.015625f;
  const float d   = ov - mu;
  const float var = wredsum(d * d) * 0.015625f;
  const float on  = d * rsqrtf(var + 6.4e-4f) * gnw[c] + gnb[c];   // eps = D*1e-5
  const float s   = wredsum(rv * kv * rk[c]);
  const float yv  = (on + s * vv) * g_[fi];
  y[fi] = f2bf(yv);
}

extern "C" void kernel_launch(void* const* d_in, const int* in_sizes, int n_in,
                              void* d_out, int out_size, void* d_ws, size_t ws_size,
                              hipStream_t stream)
{
  const float* x    = (const float*)d_in[0];
  const float* x_r  = (const float*)d_in[1];
  const float* x_w  = (const float*)d_in[2];
  const float* x_k  = (const float*)d_in[3];
  const float* x_v  = (const float*)d_in[4];
  const float* x_a  = (const float*)d_in[5];
  const float* x_g  = (const float*)d_in[6];
  const float* k_k  = (const float*)d_in[7];
  const float* k_a  = (const float*)d_in[8];
  const float* r_k  = (const float*)d_in[9];
  const float* Wr   = (const float*)d_in[10];
  const float* Wk   = (const float*)d_in[11];
  const float* Wv   = (const float*)d_in[12];
  const float* Wo   = (const float*)d_in[13];
  const float* wA   = (const float*)d_in[14];
  const float* wB   = (const float*)d_in[15];
  const float* wbias= (const float*)d_in[16];
  const float* aA   = (const float*)d_in[17];
  const float* aB   = (const float*)d_in[18];
  const float* abias= (const float*)d_in[19];
  const float* gA   = (const float*)d_in[20];
  const float* gB   = (const float*)d_in[21];
  const float* gnw  = (const float*)d_in[22];
  const float* gnb  = (const float*)d_in[23];
  const float* w0b  = (const float*)d_in[24];
  const float* w0d  = (const float*)d_in[25];

  char* ws = (char*)d_ws;
  const size_t MB = 1024ull * 1024ull;
  const size_t KB = 1024ull;

  // Memory plan (max 149 MB):
  float*          pk_  = (float*)(ws + 0);                 // 0..96MB packed [r|w|k|b|-kk|v]
  unsigned short* xw_  = (unsigned short*)(ws + 0*MB);     // in pk, dead before pk writes
  unsigned short* xa_  = (unsigned short*)(ws + 8*MB);     // in pk
  unsigned short* xg_  = (unsigned short*)(ws + 16*MB);    // in pk
  float*          g_   = (float*)(ws + 96*MB);             // 96..112
  unsigned short* xr_  = (unsigned short*)(ws + 96*MB);    // in g_, dead before g_ write
  unsigned short* xk_  = (unsigned short*)(ws + 104*MB);   // in g_
  unsigned short* y_   = (unsigned short*)(ws + 112*MB);   // 112..120
  unsigned short* xv_  = (unsigned short*)(ws + 112*MB);   // in y_, dead before y write
  unsigned short* wbf_ = (unsigned short*)(ws + 120*MB);   // 120..130 (9.6MB)
  unsigned short* wl1_ = (unsigned short*)(ws + 130*MB);
  unsigned short* al1_ = (unsigned short*)(ws + 130*MB + 512*KB);
  unsigned short* gl1_ = (unsigned short*)(ws + 131*MB);   // 1.25MB
  float*          w0_  = (float*)(ws + 132*MB + 512*KB);
  float*          o_   = (float*)(ws + 133*MB);            // 133..149

  const unsigned short* bWr = wbf_ + 0;
  const unsigned short* bWk = wbf_ + 1048576;
  const unsigned short* bWv = wbf_ + 2097152;
  const unsigned short* bWo = wbf_ + 3145728;
  const unsigned short* bwA = wbf_ + 4194304;
  const unsigned short* bwB = wbf_ + 4259840;
  const unsigned short* baA = wbf_ + 4325376;
  const unsigned short* baB = wbf_ + 4390912;
  const unsigned short* bgA = wbf_ + 4456448;
  const unsigned short* bgB = wbf_ + 4620288;

  const dim3 blk(256);
  const dim3 gBig(8, 64), gN64(1, 64), gN160(2, 64);

  w0_scan_k<<<dim3(1), dim3(1024), 0, stream>>>(w0b, w0d, w0_);

  WCvtArgs wargs;
  wargs.src[0]=Wr; wargs.src[1]=Wk; wargs.src[2]=Wv; wargs.src[3]=Wo;
  wargs.src[4]=wA; wargs.src[5]=wB; wargs.src[6]=aA; wargs.src[7]=aB;
  wargs.src[8]=gA; wargs.src[9]=gB;
  wcvt_k<<<dim3(WTOT/4/256), blk, 0, stream>>>(wargs, wbf_);

  prep_k<<<dim3(4096), blk, 0, stream>>>(x, x_r, x_w, x_k, x_v, x_a, x_g,
                                         xr_, xw_, xk_, xv_, xa_, xg_);

  // LoRA stage-1 first (xw/xa/xg die before pk is written)
  gemm_k<EPI_TANH_BF16,0><<<gN64, blk, 0, stream>>>(xw_, bwA, wl1_, nullptr, nullptr, 4096, 64, 1024);
  gemm_k<EPI_BF16,0><<<gN64, blk, 0, stream>>>(xa_, baA, al1_, nullptr, nullptr, 4096, 64, 1024);
  gemm_k<EPI_SIG_BF16,0><<<gN160, blk, 0, stream>>>(xg_, bgA, gl1_, nullptr, nullptr, 4096, 160, 1024);

  // projections -> pk slots
  gemm_k<EPI_PK_F32,0><<<gBig, blk, 0, stream>>>(xr_, bWr, pk_, nullptr, nullptr, 4096, 1024, 1024);
  gemm_k<EPI_PK_F32,2><<<gBig, blk, 0, stream>>>(xk_, bWk, pk_, nullptr, nullptr, 4096, 1024, 1024);
  gemm_k<EPI_PK_F32,5><<<gBig, blk, 0, stream>>>(xv_, bWv, pk_, nullptr, nullptr, 4096, 1024, 1024);

  // LoRA stage-2 -> pk slots (decay into arr1, a into arr3)
  gemm_k<EPI_PK_DECAY,1><<<gBig, blk, 0, stream>>>(wl1_, bwB, pk_, wbias, w0_, 4096, 1024, 64);
  gemm_k<EPI_PK_SIG,3><<<gBig, blk, 0, stream>>>(al1_, baB, pk_, abias, nullptr, 4096, 1024, 64);

  // gate -> flat g_
  gemm_k<EPI_F32,0><<<gBig, blk, 0, stream>>>(gl1_, bgB, g_, nullptr, nullptr, 4096, 1024, 160);

  // k/b/kk finalize inside pk
  kkprep2_k<<<dim3(16384), blk, 0, stream>>>(pk_, k_k, k_a);

  // sequential recurrence (ring-32, 2-step double-buffered pairs)
  scan_k<<<dim3(512), dim3(64), 0, stream>>>(pk_, o_);

  // GroupNorm + bonus + gate
  gnout_k<<<dim3(16384), blk, 0, stream>>>(pk_, o_, g_, r_k, gnw, gnb, y_);

  // output projection
  gemm_k<EPI_F32,0><<<gBig, blk, 0, stream>>>(y_, bWo, (float*)d_out, nullptr, nullptr, 4096, 1024, 1024);
}